// Round 1
// baseline (542.510 us; speedup 1.0000x reference)
//
#include <hip/hip_runtime.h>
#include <hip/hip_bf16.h>
#include <math.h>

// ---------------------------------------------------------------------------
// Transformer block (B=2, T=2048, C=1024, NH=16, hd=64), fp32 in/out.
// All matmuls in bf16 MFMA (16x16x32), fp32 accumulate.
// Pipeline:
//   1..6: transpose+cast weights fp32[K][N] -> bf16[N][K]
//   7: LN1(x) -> xn (bf16)
//   8: fused QKV GEMM  (M=4096, N=3072, K=1024) -> Q,K,V bf16 [4096][1024]
//   9: flash attention (MFMA, online softmax)   -> O bf16
//  10: O @ Wo + bo + x  -> x1 fp32
//  11: LN2(x1) -> h2 bf16
//  12: h2 @ W1 + b1, exact GELU -> H bf16 [4096][4096]
//  13: H @ W2 + b2 + x1 -> d_out fp32
// Workspace: 88 MB (H aliases dead xn/Q/K/V region).
// ---------------------------------------------------------------------------

typedef __bf16 bf16x8 __attribute__((ext_vector_type(8)));
typedef float f32x4 __attribute__((ext_vector_type(4)));

__device__ __forceinline__ unsigned short f2bf(float f) {
  union { float f; unsigned int u; } v; v.f = f;
  unsigned int u = v.u;
  unsigned int r = (u + 0x7fffu + ((u >> 16) & 1u)) >> 16;  // RNE
  return (unsigned short)r;
}

__device__ __forceinline__ bf16x8 ld_bf16x8(const unsigned short* p) {
  union { uint4 u; bf16x8 v; } x;
  x.u = *(const uint4*)p;
  return x.v;
}

// --------------------------- weight transpose+cast -------------------------
// W fp32 [K][N] -> Wt bf16 [N][K].  grid (N/32, K/32), 256 thr.
__global__ __launch_bounds__(256) void transpose_cast_kernel(
    const float* __restrict__ W, unsigned short* __restrict__ Wt, int N, int K) {
  __shared__ unsigned short tile[32][33];
  const int n0 = blockIdx.x * 32, k0 = blockIdx.y * 32;
  const int t = threadIdx.x;
  const int r = t >> 3, cq = (t & 7) * 4;
  float4 v = *(const float4*)&W[(size_t)(k0 + r) * N + n0 + cq];
  tile[cq + 0][r] = f2bf(v.x);
  tile[cq + 1][r] = f2bf(v.y);
  tile[cq + 2][r] = f2bf(v.z);
  tile[cq + 3][r] = f2bf(v.w);
  __syncthreads();
  ushort4 o;
  o.x = tile[r][cq + 0];
  o.y = tile[r][cq + 1];
  o.z = tile[r][cq + 2];
  o.w = tile[r][cq + 3];
  *(ushort4*)&Wt[(size_t)(n0 + r) * K + k0 + cq] = o;
}

// --------------------------------- layernorm -------------------------------
// 1 block per token row of 1024 fp32 -> bf16 out.
__global__ __launch_bounds__(256) void ln_kernel(
    const float* __restrict__ x, const float* __restrict__ g,
    const float* __restrict__ b, unsigned short* __restrict__ out) {
  const int row = blockIdx.x, t = threadIdx.x;
  const float4 v = ((const float4*)(x + (size_t)row * 1024))[t];
  float s = v.x + v.y + v.z + v.w;
  float s2 = v.x * v.x + v.y * v.y + v.z * v.z + v.w * v.w;
  for (int o = 32; o > 0; o >>= 1) {
    s += __shfl_xor(s, o, 64);
    s2 += __shfl_xor(s2, o, 64);
  }
  __shared__ float red[8];
  const int w = t >> 6;
  if ((t & 63) == 0) { red[w] = s; red[4 + w] = s2; }
  __syncthreads();
  s = red[0] + red[1] + red[2] + red[3];
  s2 = red[4] + red[5] + red[6] + red[7];
  const float mu = s * (1.f / 1024.f);
  const float var = s2 * (1.f / 1024.f) - mu * mu;
  const float rs = rsqrtf(var + 1e-5f);
  const float4 gg = ((const float4*)g)[t];
  const float4 bb = ((const float4*)b)[t];
  ushort4 o4;
  o4.x = f2bf((v.x - mu) * rs * gg.x + bb.x);
  o4.y = f2bf((v.y - mu) * rs * gg.y + bb.y);
  o4.z = f2bf((v.z - mu) * rs * gg.z + bb.z);
  o4.w = f2bf((v.w - mu) * rs * gg.w + bb.w);
  ((ushort4*)(out + (size_t)row * 1024))[t] = o4;
}

// ----------------------------------- GEMM ----------------------------------
// C = A[M][K](bf16) * Bt[N][K](bf16)^T with per-mode epilogue.
// 128x128 tile, BK=32, 256 thr (4 waves, 2x2 of 64x64), 16x16x32 MFMA.
enum { MODE_QKV = 0, MODE_RES = 1, MODE_GELU = 2 };

template <int MODE>
__global__ __launch_bounds__(256) void gemm_kernel(
    const unsigned short* __restrict__ A, const unsigned short* __restrict__ Bt,
    const float* __restrict__ bias0, const float* __restrict__ bias1,
    const float* __restrict__ bias2, const float* __restrict__ residual,
    void* __restrict__ out0, void* __restrict__ out1, void* __restrict__ out2,
    int M, int N, int K) {
  __shared__ __align__(16) unsigned short As[128 * 32];
  __shared__ __align__(16) unsigned short Bs[128 * 32];
  const int t = threadIdx.x;
  const int m0 = blockIdx.y * 128, n0 = blockIdx.x * 128;
  const int l = t & 63, w = t >> 6;
  const int wm = (w >> 1) * 64, wn = (w & 1) * 64;
  const int lr = l & 15, lq = l >> 4;

  f32x4 acc[4][4];
#pragma unroll
  for (int i = 0; i < 4; i++)
#pragma unroll
    for (int j = 0; j < 4; j++) {
      f32x4 z = {0.f, 0.f, 0.f, 0.f};
      acc[i][j] = z;
    }

  for (int k0 = 0; k0 < K; k0 += 32) {
    __syncthreads();
#pragma unroll
    for (int s = 0; s < 2; s++) {
      const int c = t + s * 256;
      const int row = c >> 2, c8 = (c & 3) * 8;
      *(uint4*)&As[row * 32 + c8] =
          *(const uint4*)&A[(size_t)(m0 + row) * K + k0 + c8];
      *(uint4*)&Bs[row * 32 + c8] =
          *(const uint4*)&Bt[(size_t)(n0 + row) * K + k0 + c8];
    }
    __syncthreads();
    bf16x8 af[4], bf[4];
#pragma unroll
    for (int mi = 0; mi < 4; mi++)
      af[mi] = ld_bf16x8(&As[(wm + mi * 16 + lr) * 32 + lq * 8]);
#pragma unroll
    for (int ni = 0; ni < 4; ni++)
      bf[ni] = ld_bf16x8(&Bs[(wn + ni * 16 + lr) * 32 + lq * 8]);
#pragma unroll
    for (int mi = 0; mi < 4; mi++)
#pragma unroll
      for (int ni = 0; ni < 4; ni++)
        acc[mi][ni] = __builtin_amdgcn_mfma_f32_16x16x32_bf16(
            af[mi], bf[ni], acc[mi][ni], 0, 0, 0);
  }

#pragma unroll
  for (int mi = 0; mi < 4; mi++) {
#pragma unroll
    for (int ni = 0; ni < 4; ni++) {
#pragma unroll
      for (int i = 0; i < 4; i++) {
        const int gm = m0 + wm + mi * 16 + lq * 4 + i;
        const int gn = n0 + wn + ni * 16 + lr;
        const float v = acc[mi][ni][i];
        if (MODE == MODE_QKV) {
          const int sel = gn >> 10, cn = gn & 1023;
          const float* bb = sel == 0 ? bias0 : (sel == 1 ? bias1 : bias2);
          unsigned short* dst =
              (unsigned short*)(sel == 0 ? out0 : (sel == 1 ? out1 : out2));
          dst[(size_t)gm * 1024 + cn] = f2bf(v + bb[cn]);
        } else if (MODE == MODE_RES) {
          ((float*)out0)[(size_t)gm * N + gn] =
              v + bias0[gn] + residual[(size_t)gm * N + gn];
        } else {  // MODE_GELU, exact
          const float u = v + bias0[gn];
          const float ge = 0.5f * u * (1.f + erff(u * 0.70710678118654752f));
          ((unsigned short*)out0)[(size_t)gm * N + gn] = f2bf(ge);
        }
      }
    }
  }
}

// ------------------------------ flash attention ----------------------------
// grid (32 q-tiles, 32 b*h). Q/K/V bf16 [4096][1024], head cols h*64..h*64+63.
// Per block: 64 queries; per wave 16 queries. Key tiles of 64, online softmax.
// LDS row stride 96 bf16 (=48 dwords -> 2-way bank aliasing, free; 16B aligned).
__global__ __launch_bounds__(256) void attn_kernel(
    const unsigned short* __restrict__ Q, const unsigned short* __restrict__ Kt,
    const unsigned short* __restrict__ V, unsigned short* __restrict__ O) {
  __shared__ __align__(16) unsigned short Qs[64 * 96];
  __shared__ __align__(16) unsigned short Ks[64 * 96];
  __shared__ __align__(16) unsigned short Vt[64 * 96];
  __shared__ __align__(16) unsigned short Ps[64 * 96];
  const int qt = blockIdx.x;
  const int bh = blockIdx.y;
  const int bb = bh >> 4, h = bh & 15;
  const int t = threadIdx.x, l = t & 63, w = t >> 6;
  const int lr = l & 15, lq = l >> 4;
  const size_t rowBase = (size_t)bb * 2048;
  const int col0 = h * 64;

  // stage Q tile (64x64): 512 16B chunks
#pragma unroll
  for (int s = 0; s < 2; s++) {
    const int c = t + s * 256;
    const int r = c >> 3, c8 = (c & 7) * 8;
    *(uint4*)&Qs[r * 96 + c8] =
        *(const uint4*)&Q[(rowBase + qt * 64 + r) * 1024 + col0 + c8];
  }
  __syncthreads();
  bf16x8 qf[2];
#pragma unroll
  for (int kk = 0; kk < 2; kk++)
    qf[kk] = ld_bf16x8(&Qs[(w * 16 + lr) * 96 + kk * 32 + lq * 8]);

  f32x4 oacc[4];
#pragma unroll
  for (int nt = 0; nt < 4; nt++) {
    f32x4 z = {0.f, 0.f, 0.f, 0.f};
    oacc[nt] = z;
  }
  float mi_[4] = {-1e30f, -1e30f, -1e30f, -1e30f};
  float li[4] = {0.f, 0.f, 0.f, 0.f};

  for (int kt = 0; kt < 2048; kt += 64) {
    __syncthreads();
#pragma unroll
    for (int s = 0; s < 2; s++) {
      const int c = t + s * 256;
      const int r = c >> 3, c8 = (c & 7) * 8;
      *(uint4*)&Ks[r * 96 + c8] =
          *(const uint4*)&Kt[(rowBase + kt + r) * 1024 + col0 + c8];
      uint4 vv = *(const uint4*)&V[(rowBase + kt + r) * 1024 + col0 + c8];
      const unsigned short* vp = (const unsigned short*)&vv;
#pragma unroll
      for (int j = 0; j < 8; j++) Vt[(c8 + j) * 96 + r] = vp[j];  // V^T
    }
    __syncthreads();

    // S = Q K^T  (16 queries x 64 keys per wave)
    f32x4 sc[4];
#pragma unroll
    for (int nt = 0; nt < 4; nt++) {
      f32x4 z = {0.f, 0.f, 0.f, 0.f};
      sc[nt] = z;
    }
#pragma unroll
    for (int nt = 0; nt < 4; nt++)
#pragma unroll
      for (int kk = 0; kk < 2; kk++) {
        bf16x8 kf = ld_bf16x8(&Ks[(nt * 16 + lr) * 96 + kk * 32 + lq * 8]);
        sc[nt] = __builtin_amdgcn_mfma_f32_16x16x32_bf16(qf[kk], kf, sc[nt], 0, 0, 0);
      }
#pragma unroll
    for (int nt = 0; nt < 4; nt++) sc[nt] = sc[nt] * 0.125f;  // 1/sqrt(64)

    // online softmax; row r=(lq*4+i) cols spread over 16-lane group
#pragma unroll
    for (int i = 0; i < 4; i++) {
      float mx = fmaxf(fmaxf(sc[0][i], sc[1][i]), fmaxf(sc[2][i], sc[3][i]));
#pragma unroll
      for (int o = 1; o < 16; o <<= 1) mx = fmaxf(mx, __shfl_xor(mx, o, 16));
      const float mnew = fmaxf(mi_[i], mx);
      const float alpha = __expf(mi_[i] - mnew);
      mi_[i] = mnew;
      float rsum = 0.f;
#pragma unroll
      for (int nt = 0; nt < 4; nt++) {
        const float p = __expf(sc[nt][i] - mnew);
        sc[nt][i] = p;
        rsum += p;
      }
#pragma unroll
      for (int o = 1; o < 16; o <<= 1) rsum += __shfl_xor(rsum, o, 16);
      li[i] = li[i] * alpha + rsum;
#pragma unroll
      for (int nt = 0; nt < 4; nt++) oacc[nt][i] *= alpha;
    }

    // P: C-layout -> LDS -> A-layout (per-wave private region, in-wave dep)
#pragma unroll
    for (int nt = 0; nt < 4; nt++)
#pragma unroll
      for (int i = 0; i < 4; i++)
        Ps[(w * 16 + lq * 4 + i) * 96 + nt * 16 + lr] = f2bf(sc[nt][i]);
    bf16x8 pf[2];
#pragma unroll
    for (int kk = 0; kk < 2; kk++)
      pf[kk] = ld_bf16x8(&Ps[(w * 16 + lr) * 96 + kk * 32 + lq * 8]);
#pragma unroll
    for (int nt = 0; nt < 4; nt++)
#pragma unroll
      for (int kk = 0; kk < 2; kk++) {
        bf16x8 vf = ld_bf16x8(&Vt[(nt * 16 + lr) * 96 + kk * 32 + lq * 8]);
        oacc[nt] = __builtin_amdgcn_mfma_f32_16x16x32_bf16(pf[kk], vf, oacc[nt], 0, 0, 0);
      }
  }

#pragma unroll
  for (int i = 0; i < 4; i++) {
    const float inv = 1.f / li[i];
#pragma unroll
    for (int nt = 0; nt < 4; nt++) {
      const size_t orow = rowBase + qt * 64 + w * 16 + lq * 4 + i;
      const int ocol = col0 + nt * 16 + lr;
      O[orow * 1024 + ocol] = f2bf(oacc[nt][i] * inv);
    }
  }
}

// --------------------------------- launcher --------------------------------
extern "C" void kernel_launch(void* const* d_in, const int* in_sizes, int n_in,
                              void* d_out, int out_size, void* d_ws, size_t ws_size,
                              hipStream_t stream) {
  const float* x    = (const float*)d_in[0];
  const float* Wq   = (const float*)d_in[1];
  const float* bq   = (const float*)d_in[2];
  const float* Wk   = (const float*)d_in[3];
  const float* bk   = (const float*)d_in[4];
  const float* Wv   = (const float*)d_in[5];
  const float* bv   = (const float*)d_in[6];
  const float* Wo   = (const float*)d_in[7];
  const float* bo   = (const float*)d_in[8];
  const float* W1   = (const float*)d_in[9];
  const float* b1   = (const float*)d_in[10];
  const float* W2   = (const float*)d_in[11];
  const float* b2   = (const float*)d_in[12];
  const float* ln1g = (const float*)d_in[13];
  const float* ln1b = (const float*)d_in[14];
  const float* ln2g = (const float*)d_in[15];
  const float* ln2b = (const float*)d_in[16];

  char* ws = (char*)d_ws;
  const size_t MB = 1024ull * 1024ull;
  unsigned short* WqT = (unsigned short*)(ws + 0 * MB);   // 2MB  \  contiguous:
  unsigned short* WkT = (unsigned short*)(ws + 2 * MB);   // 2MB   } fused QKV B
  unsigned short* WvT = (unsigned short*)(ws + 4 * MB);   // 2MB  /  [3072][1024]
  unsigned short* WoT = (unsigned short*)(ws + 6 * MB);   // 2MB
  unsigned short* W1T = (unsigned short*)(ws + 8 * MB);   // 8MB [4096][1024]
  unsigned short* W2T = (unsigned short*)(ws + 16 * MB);  // 8MB [1024][4096]
  unsigned short* xn  = (unsigned short*)(ws + 24 * MB);  // 8MB
  unsigned short* Qb  = (unsigned short*)(ws + 32 * MB);  // 8MB
  unsigned short* Kb  = (unsigned short*)(ws + 40 * MB);  // 8MB
  unsigned short* Vb  = (unsigned short*)(ws + 48 * MB);  // 8MB
  unsigned short* Ob  = (unsigned short*)(ws + 56 * MB);  // 8MB
  float*          x1  = (float*)(ws + 64 * MB);           // 16MB
  unsigned short* h2  = (unsigned short*)(ws + 80 * MB);  // 8MB  (total 88MB)
  unsigned short* Hb  = (unsigned short*)(ws + 24 * MB);  // 32MB alias xn/Q/K/V

  const dim3 blk(256);

  transpose_cast_kernel<<<dim3(32, 32), blk, 0, stream>>>(Wq, WqT, 1024, 1024);
  transpose_cast_kernel<<<dim3(32, 32), blk, 0, stream>>>(Wk, WkT, 1024, 1024);
  transpose_cast_kernel<<<dim3(32, 32), blk, 0, stream>>>(Wv, WvT, 1024, 1024);
  transpose_cast_kernel<<<dim3(32, 32), blk, 0, stream>>>(Wo, WoT, 1024, 1024);
  transpose_cast_kernel<<<dim3(128, 32), blk, 0, stream>>>(W1, W1T, 4096, 1024);
  transpose_cast_kernel<<<dim3(32, 128), blk, 0, stream>>>(W2, W2T, 1024, 4096);

  ln_kernel<<<4096, blk, 0, stream>>>(x, ln1g, ln1b, xn);

  gemm_kernel<MODE_QKV><<<dim3(3072 / 128, 4096 / 128), blk, 0, stream>>>(
      xn, WqT, bq, bk, bv, nullptr, Qb, Kb, Vb, 4096, 3072, 1024);

  attn_kernel<<<dim3(32, 32), blk, 0, stream>>>(Qb, Kb, Vb, Ob);

  gemm_kernel<MODE_RES><<<dim3(1024 / 128, 4096 / 128), blk, 0, stream>>>(
      Ob, WoT, bo, nullptr, nullptr, x, x1, nullptr, nullptr, 4096, 1024, 1024);

  ln_kernel<<<4096, blk, 0, stream>>>(x1, ln2g, ln2b, h2);

  gemm_kernel<MODE_GELU><<<dim3(4096 / 128, 4096 / 128), blk, 0, stream>>>(
      h2, W1T, b1, nullptr, nullptr, nullptr, Hb, nullptr, nullptr, 4096, 4096, 1024);

  gemm_kernel<MODE_RES><<<dim3(1024 / 128, 4096 / 128), blk, 0, stream>>>(
      Hb, W2T, b2, nullptr, nullptr, x1, (float*)d_out, nullptr, nullptr, 4096, 1024, 4096);
}

// Round 2
// 506.637 us; speedup vs baseline: 1.0708x; 1.0708x over previous
//
#include <hip/hip_runtime.h>
#include <hip/hip_bf16.h>
#include <math.h>

// ---------------------------------------------------------------------------
// Transformer block (B=2, T=2048, C=1024, NH=16, hd=64), fp32 in/out.
// All matmuls in bf16 MFMA (16x16x32), fp32 accumulate.
// R2 changes vs R1:
//  - attention: V pre-transposed globally (no in-kernel 8-way-conflict
//    scatter), LDS stride 96->72 (36KB -> 4 blocks/CU), exp2-domain softmax,
//    deferred row-sum reduction.
//  - GEMM: global_load_lds width=16 staging (m97 ladder step, 1.69x).
// ---------------------------------------------------------------------------

typedef __bf16 bf16x8 __attribute__((ext_vector_type(8)));
typedef float f32x4 __attribute__((ext_vector_type(4)));

__device__ __forceinline__ unsigned short f2bf(float f) {
  union { float f; unsigned int u; } v; v.f = f;
  unsigned int u = v.u;
  unsigned int r = (u + 0x7fffu + ((u >> 16) & 1u)) >> 16;  // RNE
  return (unsigned short)r;
}

__device__ __forceinline__ bf16x8 ld_bf16x8(const unsigned short* p) {
  union { uint4 u; bf16x8 v; } x;
  x.u = *(const uint4*)p;
  return x.v;
}

// async 16B global->LDS (DMA, no VGPR round-trip). LDS dest must be
// wave-uniform base + lane*16 — caller guarantees contiguous lane order.
__device__ __forceinline__ void async_copy16(const void* g, void* l) {
  __builtin_amdgcn_global_load_lds(
      (const __attribute__((address_space(1))) void*)g,
      (__attribute__((address_space(3))) void*)l, 16, 0, 0);
}

// --------------------------- weight transpose+cast -------------------------
// W fp32 [K][N] -> Wt bf16 [N][K].  grid (N/32, K/32), 256 thr.
__global__ __launch_bounds__(256) void transpose_cast_kernel(
    const float* __restrict__ W, unsigned short* __restrict__ Wt, int N, int K) {
  __shared__ unsigned short tile[32][33];
  const int n0 = blockIdx.x * 32, k0 = blockIdx.y * 32;
  const int t = threadIdx.x;
  const int r = t >> 3, cq = (t & 7) * 4;
  float4 v = *(const float4*)&W[(size_t)(k0 + r) * N + n0 + cq];
  tile[cq + 0][r] = f2bf(v.x);
  tile[cq + 1][r] = f2bf(v.y);
  tile[cq + 2][r] = f2bf(v.z);
  tile[cq + 3][r] = f2bf(v.w);
  __syncthreads();
  ushort4 o;
  o.x = tile[r][cq + 0];
  o.y = tile[r][cq + 1];
  o.z = tile[r][cq + 2];
  o.w = tile[r][cq + 3];
  *(ushort4*)&Wt[(size_t)(n0 + r) * K + k0 + cq] = o;
}

// ------------------------------- V transpose -------------------------------
// V bf16 [4096][1024] -> Vt bf16 [32 bh][64 d][2048 k]. grid (64, 2, 32).
__global__ __launch_bounds__(256) void transpose_v_kernel(
    const unsigned short* __restrict__ V, unsigned short* __restrict__ Vt) {
  __shared__ unsigned short tile[32][36];
  const int kt = blockIdx.x * 32;
  const int d0 = blockIdx.y * 32;
  const int bh = blockIdx.z;
  const int bb = bh >> 4, h = bh & 15;
  const int t = threadIdx.x;
  const int r = t >> 3, c4 = (t & 7) * 4;
  ushort4 v = *(const ushort4*)&V[((size_t)bb * 2048 + kt + r) * 1024 + h * 64 + d0 + c4];
  tile[c4 + 0][r] = v.x;
  tile[c4 + 1][r] = v.y;
  tile[c4 + 2][r] = v.z;
  tile[c4 + 3][r] = v.w;
  __syncthreads();
  ushort4 o;
  o.x = tile[r][c4 + 0];
  o.y = tile[r][c4 + 1];
  o.z = tile[r][c4 + 2];
  o.w = tile[r][c4 + 3];
  *(ushort4*)&Vt[((size_t)bh * 64 + d0 + r) * 2048 + kt + c4] = o;
}

// --------------------------------- layernorm -------------------------------
__global__ __launch_bounds__(256) void ln_kernel(
    const float* __restrict__ x, const float* __restrict__ g,
    const float* __restrict__ b, unsigned short* __restrict__ out) {
  const int row = blockIdx.x, t = threadIdx.x;
  const float4 v = ((const float4*)(x + (size_t)row * 1024))[t];
  float s = v.x + v.y + v.z + v.w;
  float s2 = v.x * v.x + v.y * v.y + v.z * v.z + v.w * v.w;
  for (int o = 32; o > 0; o >>= 1) {
    s += __shfl_xor(s, o, 64);
    s2 += __shfl_xor(s2, o, 64);
  }
  __shared__ float red[8];
  const int w = t >> 6;
  if ((t & 63) == 0) { red[w] = s; red[4 + w] = s2; }
  __syncthreads();
  s = red[0] + red[1] + red[2] + red[3];
  s2 = red[4] + red[5] + red[6] + red[7];
  const float mu = s * (1.f / 1024.f);
  const float var = s2 * (1.f / 1024.f) - mu * mu;
  const float rs = rsqrtf(var + 1e-5f);
  const float4 gg = ((const float4*)g)[t];
  const float4 bb = ((const float4*)b)[t];
  ushort4 o4;
  o4.x = f2bf((v.x - mu) * rs * gg.x + bb.x);
  o4.y = f2bf((v.y - mu) * rs * gg.y + bb.y);
  o4.z = f2bf((v.z - mu) * rs * gg.z + bb.z);
  o4.w = f2bf((v.w - mu) * rs * gg.w + bb.w);
  ((ushort4*)(out + (size_t)row * 1024))[t] = o4;
}

// ----------------------------------- GEMM ----------------------------------
// C = A[M][K](bf16) * Bt[N][K](bf16)^T with per-mode epilogue.
// 128x128 tile, BK=32, 256 thr (4 waves, 2x2 of 64x64), 16x16x32 MFMA.
// Staging via global_load_lds width=16: LDS offset = lane*16B, contiguous.
enum { MODE_QKV = 0, MODE_RES = 1, MODE_GELU = 2 };

template <int MODE>
__global__ __launch_bounds__(256) void gemm_kernel(
    const unsigned short* __restrict__ A, const unsigned short* __restrict__ Bt,
    const float* __restrict__ bias0, const float* __restrict__ bias1,
    const float* __restrict__ bias2, const float* __restrict__ residual,
    void* __restrict__ out0, void* __restrict__ out1, void* __restrict__ out2,
    int M, int N, int K) {
  __shared__ __align__(16) unsigned short As[128 * 32];
  __shared__ __align__(16) unsigned short Bs[128 * 32];
  const int t = threadIdx.x;
  const int m0 = blockIdx.y * 128, n0 = blockIdx.x * 128;
  const int l = t & 63, w = t >> 6;
  const int wm = (w >> 1) * 64, wn = (w & 1) * 64;
  const int lr = l & 15, lq = l >> 4;

  f32x4 acc[4][4];
#pragma unroll
  for (int i = 0; i < 4; i++)
#pragma unroll
    for (int j = 0; j < 4; j++) {
      f32x4 z = {0.f, 0.f, 0.f, 0.f};
      acc[i][j] = z;
    }

  for (int k0 = 0; k0 < K; k0 += 32) {
    __syncthreads();
#pragma unroll
    for (int s = 0; s < 2; s++) {
      const int c = t + s * 256;
      const int row = c >> 2, c8 = (c & 3) * 8;
      async_copy16(&A[(size_t)(m0 + row) * K + k0 + c8], &As[c * 8]);
      async_copy16(&Bt[(size_t)(n0 + row) * K + k0 + c8], &Bs[c * 8]);
    }
    __syncthreads();
    bf16x8 af[4], bf[4];
#pragma unroll
    for (int mi = 0; mi < 4; mi++)
      af[mi] = ld_bf16x8(&As[(wm + mi * 16 + lr) * 32 + lq * 8]);
#pragma unroll
    for (int ni = 0; ni < 4; ni++)
      bf[ni] = ld_bf16x8(&Bs[(wn + ni * 16 + lr) * 32 + lq * 8]);
#pragma unroll
    for (int mi = 0; mi < 4; mi++)
#pragma unroll
      for (int ni = 0; ni < 4; ni++)
        acc[mi][ni] = __builtin_amdgcn_mfma_f32_16x16x32_bf16(
            af[mi], bf[ni], acc[mi][ni], 0, 0, 0);
  }

#pragma unroll
  for (int mi = 0; mi < 4; mi++) {
#pragma unroll
    for (int ni = 0; ni < 4; ni++) {
#pragma unroll
      for (int i = 0; i < 4; i++) {
        const int gm = m0 + wm + mi * 16 + lq * 4 + i;
        const int gn = n0 + wn + ni * 16 + lr;
        const float v = acc[mi][ni][i];
        if (MODE == MODE_QKV) {
          const int sel = gn >> 10, cn = gn & 1023;
          const float* bb = sel == 0 ? bias0 : (sel == 1 ? bias1 : bias2);
          unsigned short* dst =
              (unsigned short*)(sel == 0 ? out0 : (sel == 1 ? out1 : out2));
          dst[(size_t)gm * 1024 + cn] = f2bf(v + bb[cn]);
        } else if (MODE == MODE_RES) {
          ((float*)out0)[(size_t)gm * N + gn] =
              v + bias0[gn] + residual[(size_t)gm * N + gn];
        } else {  // MODE_GELU, exact
          const float u = v + bias0[gn];
          const float ge = 0.5f * u * (1.f + erff(u * 0.70710678118654752f));
          ((unsigned short*)out0)[(size_t)gm * N + gn] = f2bf(ge);
        }
      }
    }
  }
}

// ------------------------------ flash attention ----------------------------
// grid (32 q-tiles, 32 b*h). Q/K bf16 [4096][1024]; Vt bf16 [32][64][2048].
// Per block: 64 queries (16/wave); key tiles of 64; online softmax in exp2
// domain. LDS stride 72 shorts (16B-aligned; 2-way bank aliasing = free).
__global__ __launch_bounds__(256) void attn_kernel(
    const unsigned short* __restrict__ Q, const unsigned short* __restrict__ Kt,
    const unsigned short* __restrict__ Vt, unsigned short* __restrict__ O) {
  __shared__ __align__(16) unsigned short Qs[64 * 72];
  __shared__ __align__(16) unsigned short Ks[64 * 72];
  __shared__ __align__(16) unsigned short Vs[64 * 72];
  __shared__ __align__(16) unsigned short Ps[64 * 72];
  const int qt = blockIdx.x;
  const int bh = blockIdx.y;
  const int bb = bh >> 4, h = bh & 15;
  const int t = threadIdx.x, l = t & 63, w = t >> 6;
  const int lr = l & 15, lq = l >> 4;
  const size_t rowBase = (size_t)bb * 2048;
  const int col0 = h * 64;
  const float SCL2 = 0.125f * 1.44269504088896f;  // (1/sqrt(64))*log2(e)

  // stage Q tile (64x64)
#pragma unroll
  for (int s = 0; s < 2; s++) {
    const int c = t + s * 256;
    const int r = c >> 3, c8 = (c & 7) * 8;
    *(uint4*)&Qs[r * 72 + c8] =
        *(const uint4*)&Q[(rowBase + qt * 64 + r) * 1024 + col0 + c8];
  }
  __syncthreads();
  bf16x8 qf[2];
#pragma unroll
  for (int kk = 0; kk < 2; kk++)
    qf[kk] = ld_bf16x8(&Qs[(w * 16 + lr) * 72 + kk * 32 + lq * 8]);

  f32x4 oacc[4];
#pragma unroll
  for (int nt = 0; nt < 4; nt++) {
    f32x4 z = {0.f, 0.f, 0.f, 0.f};
    oacc[nt] = z;
  }
  float mi_[4] = {-1e30f, -1e30f, -1e30f, -1e30f};
  float lp[4] = {0.f, 0.f, 0.f, 0.f};  // per-lane partial row sums

  for (int kt = 0; kt < 2048; kt += 64) {
    __syncthreads();
#pragma unroll
    for (int s = 0; s < 2; s++) {
      const int c = t + s * 256;
      const int r = c >> 3, c8 = (c & 7) * 8;
      *(uint4*)&Ks[r * 72 + c8] =
          *(const uint4*)&Kt[(rowBase + kt + r) * 1024 + col0 + c8];
      *(uint4*)&Vs[r * 72 + c8] =
          *(const uint4*)&Vt[((size_t)bh * 64 + r) * 2048 + kt + c8];
    }
    __syncthreads();

    // S = Q K^T  (16 queries x 64 keys per wave), scaled into exp2 domain
    f32x4 sc[4];
#pragma unroll
    for (int nt = 0; nt < 4; nt++) {
      f32x4 z = {0.f, 0.f, 0.f, 0.f};
      sc[nt] = z;
    }
#pragma unroll
    for (int nt = 0; nt < 4; nt++)
#pragma unroll
      for (int kk = 0; kk < 2; kk++) {
        bf16x8 kf = ld_bf16x8(&Ks[(nt * 16 + lr) * 72 + kk * 32 + lq * 8]);
        sc[nt] = __builtin_amdgcn_mfma_f32_16x16x32_bf16(qf[kk], kf, sc[nt], 0, 0, 0);
      }
#pragma unroll
    for (int nt = 0; nt < 4; nt++) sc[nt] = sc[nt] * SCL2;

    // online softmax (exp2 domain); row r=(lq*4+i), cols across 16-lane group
#pragma unroll
    for (int i = 0; i < 4; i++) {
      float mx = fmaxf(fmaxf(sc[0][i], sc[1][i]), fmaxf(sc[2][i], sc[3][i]));
#pragma unroll
      for (int o = 1; o < 16; o <<= 1) mx = fmaxf(mx, __shfl_xor(mx, o, 16));
      const float mnew = fmaxf(mi_[i], mx);
      const float alpha = exp2f(mi_[i] - mnew);
      mi_[i] = mnew;
      float rsum = 0.f;
#pragma unroll
      for (int nt = 0; nt < 4; nt++) {
        const float p = exp2f(sc[nt][i] - mnew);
        sc[nt][i] = p;
        rsum += p;
      }
      lp[i] = lp[i] * alpha + rsum;  // per-lane partial; reduce at end
#pragma unroll
      for (int nt = 0; nt < 4; nt++) oacc[nt][i] *= alpha;
    }

    // P: C-layout -> LDS -> A-layout (per-wave private region, in-wave dep)
#pragma unroll
    for (int nt = 0; nt < 4; nt++)
#pragma unroll
      for (int i = 0; i < 4; i++)
        Ps[(w * 16 + lq * 4 + i) * 72 + nt * 16 + lr] = f2bf(sc[nt][i]);
    bf16x8 pf[2];
#pragma unroll
    for (int kk = 0; kk < 2; kk++)
      pf[kk] = ld_bf16x8(&Ps[(w * 16 + lr) * 72 + kk * 32 + lq * 8]);
#pragma unroll
    for (int nt = 0; nt < 4; nt++)
#pragma unroll
      for (int kk = 0; kk < 2; kk++) {
        bf16x8 vf = ld_bf16x8(&Vs[(nt * 16 + lr) * 72 + kk * 32 + lq * 8]);
        oacc[nt] = __builtin_amdgcn_mfma_f32_16x16x32_bf16(pf[kk], vf, oacc[nt], 0, 0, 0);
      }
  }

#pragma unroll
  for (int i = 0; i < 4; i++) {
    float li = lp[i];
#pragma unroll
    for (int o = 1; o < 16; o <<= 1) li += __shfl_xor(li, o, 16);
    const float inv = 1.f / li;
#pragma unroll
    for (int nt = 0; nt < 4; nt++) {
      const size_t orow = rowBase + qt * 64 + w * 16 + lq * 4 + i;
      const int ocol = col0 + nt * 16 + lr;
      O[orow * 1024 + ocol] = f2bf(oacc[nt][i] * inv);
    }
  }
}

// --------------------------------- launcher --------------------------------
extern "C" void kernel_launch(void* const* d_in, const int* in_sizes, int n_in,
                              void* d_out, int out_size, void* d_ws, size_t ws_size,
                              hipStream_t stream) {
  const float* x    = (const float*)d_in[0];
  const float* Wq   = (const float*)d_in[1];
  const float* bq   = (const float*)d_in[2];
  const float* Wk   = (const float*)d_in[3];
  const float* bk   = (const float*)d_in[4];
  const float* Wv   = (const float*)d_in[5];
  const float* bv   = (const float*)d_in[6];
  const float* Wo   = (const float*)d_in[7];
  const float* bo   = (const float*)d_in[8];
  const float* W1   = (const float*)d_in[9];
  const float* b1   = (const float*)d_in[10];
  const float* W2   = (const float*)d_in[11];
  const float* b2   = (const float*)d_in[12];
  const float* ln1g = (const float*)d_in[13];
  const float* ln1b = (const float*)d_in[14];
  const float* ln2g = (const float*)d_in[15];
  const float* ln2b = (const float*)d_in[16];

  char* ws = (char*)d_ws;
  const size_t MB = 1024ull * 1024ull;
  unsigned short* WqT = (unsigned short*)(ws + 0 * MB);   // 2MB  \  contiguous:
  unsigned short* WkT = (unsigned short*)(ws + 2 * MB);   // 2MB   } fused QKV B
  unsigned short* WvT = (unsigned short*)(ws + 4 * MB);   // 2MB  /  [3072][1024]
  unsigned short* WoT = (unsigned short*)(ws + 6 * MB);   // 2MB
  unsigned short* W1T = (unsigned short*)(ws + 8 * MB);   // 8MB [4096][1024]
  unsigned short* W2T = (unsigned short*)(ws + 16 * MB);  // 8MB [1024][4096]
  unsigned short* xn  = (unsigned short*)(ws + 24 * MB);  // 8MB
  unsigned short* Qb  = (unsigned short*)(ws + 32 * MB);  // 8MB
  unsigned short* Kb  = (unsigned short*)(ws + 40 * MB);  // 8MB
  unsigned short* Vb  = (unsigned short*)(ws + 48 * MB);  // 8MB
  unsigned short* Ob  = (unsigned short*)(ws + 56 * MB);  // 8MB
  float*          x1  = (float*)(ws + 64 * MB);           // 16MB
  unsigned short* h2  = (unsigned short*)(ws + 80 * MB);  // 8MB  (total 88MB)
  // aliases (regions dead by the time they're reused):
  unsigned short* VtG = (unsigned short*)(ws + 24 * MB);  // 8MB alias xn (dead after QKV GEMM)
  unsigned short* Hb  = (unsigned short*)(ws + 24 * MB);  // 32MB alias xn/Q/K/V (dead after attn+proj)

  const dim3 blk(256);

  transpose_cast_kernel<<<dim3(32, 32), blk, 0, stream>>>(Wq, WqT, 1024, 1024);
  transpose_cast_kernel<<<dim3(32, 32), blk, 0, stream>>>(Wk, WkT, 1024, 1024);
  transpose_cast_kernel<<<dim3(32, 32), blk, 0, stream>>>(Wv, WvT, 1024, 1024);
  transpose_cast_kernel<<<dim3(32, 32), blk, 0, stream>>>(Wo, WoT, 1024, 1024);
  transpose_cast_kernel<<<dim3(128, 32), blk, 0, stream>>>(W1, W1T, 4096, 1024);
  transpose_cast_kernel<<<dim3(32, 128), blk, 0, stream>>>(W2, W2T, 1024, 4096);

  ln_kernel<<<4096, blk, 0, stream>>>(x, ln1g, ln1b, xn);

  gemm_kernel<MODE_QKV><<<dim3(3072 / 128, 4096 / 128), blk, 0, stream>>>(
      xn, WqT, bq, bk, bv, nullptr, Qb, Kb, Vb, 4096, 3072, 1024);

  transpose_v_kernel<<<dim3(64, 2, 32), blk, 0, stream>>>(Vb, VtG);

  attn_kernel<<<dim3(32, 32), blk, 0, stream>>>(Qb, Kb, VtG, Ob);

  gemm_kernel<MODE_RES><<<dim3(1024 / 128, 4096 / 128), blk, 0, stream>>>(
      Ob, WoT, bo, nullptr, nullptr, x, x1, nullptr, nullptr, 4096, 1024, 1024);

  ln_kernel<<<4096, blk, 0, stream>>>(x1, ln2g, ln2b, h2);

  gemm_kernel<MODE_GELU><<<dim3(4096 / 128, 4096 / 128), blk, 0, stream>>>(
      h2, W1T, b1, nullptr, nullptr, nullptr, Hb, nullptr, nullptr, 4096, 4096, 1024);

  gemm_kernel<MODE_RES><<<dim3(1024 / 128, 4096 / 128), blk, 0, stream>>>(
      Hb, W2T, b2, nullptr, nullptr, x1, (float*)d_out, nullptr, nullptr, 4096, 1024, 4096);
}

// Round 3
// 455.215 us; speedup vs baseline: 1.1918x; 1.1130x over previous
//
#include <hip/hip_runtime.h>
#include <hip/hip_bf16.h>
#include <math.h>

// ---------------------------------------------------------------------------
// Transformer block (B=2, T=2048, C=1024, NH=16, hd=64), fp32 in/out.
// R3 changes vs R2 (attention rewrite):
//  - 128-query blocks (4 waves x 32 q): K/V LDS frags amortized 2x.
//  - S^T scheme: mfma(kf, qf) -> S^T; softmax per-lane over regs (2 shuffles
//    instead of 16); P[q][key] packs to ds_write_b64 (no scalar f2bf stores).
//  - PV: P as A-op, V^T as B-op -> O in C-layout, same coalesced-ish store.
//  - softmax scale folded into Q at QKV epilogue (Q is attention-only).
//  - Ps aliases dead Qs LDS (qf hoisted) -> LDS stays 36KB.
// ---------------------------------------------------------------------------

typedef __bf16 bf16x8 __attribute__((ext_vector_type(8)));
typedef float f32x4 __attribute__((ext_vector_type(4)));

__device__ __forceinline__ unsigned short f2bf(float f) {
  union { float f; unsigned int u; } v; v.f = f;
  unsigned int u = v.u;
  unsigned int r = (u + 0x7fffu + ((u >> 16) & 1u)) >> 16;  // RNE
  return (unsigned short)r;
}

__device__ __forceinline__ unsigned int fbits(float f) {
  union { float f; unsigned int u; } v; v.f = f;
  return v.u;
}

__device__ __forceinline__ bf16x8 ld_bf16x8(const unsigned short* p) {
  union { uint4 u; bf16x8 v; } x;
  x.u = *(const uint4*)p;
  return x.v;
}

// async 16B global->LDS (DMA, no VGPR round-trip). LDS dest is wave-uniform
// base + lane*16 — caller guarantees contiguous lane order.
__device__ __forceinline__ void async_copy16(const void* g, void* l) {
  __builtin_amdgcn_global_load_lds(
      (const __attribute__((address_space(1))) void*)g,
      (__attribute__((address_space(3))) void*)l, 16, 0, 0);
}

// --------------------------- weight transpose+cast -------------------------
__global__ __launch_bounds__(256) void transpose_cast_kernel(
    const float* __restrict__ W, unsigned short* __restrict__ Wt, int N, int K) {
  __shared__ unsigned short tile[32][33];
  const int n0 = blockIdx.x * 32, k0 = blockIdx.y * 32;
  const int t = threadIdx.x;
  const int r = t >> 3, cq = (t & 7) * 4;
  float4 v = *(const float4*)&W[(size_t)(k0 + r) * N + n0 + cq];
  tile[cq + 0][r] = f2bf(v.x);
  tile[cq + 1][r] = f2bf(v.y);
  tile[cq + 2][r] = f2bf(v.z);
  tile[cq + 3][r] = f2bf(v.w);
  __syncthreads();
  ushort4 o;
  o.x = tile[r][cq + 0];
  o.y = tile[r][cq + 1];
  o.z = tile[r][cq + 2];
  o.w = tile[r][cq + 3];
  *(ushort4*)&Wt[(size_t)(n0 + r) * K + k0 + cq] = o;
}

// ------------------------------- V transpose -------------------------------
// V bf16 [4096][1024] -> Vt bf16 [32 bh][64 d][2048 k]. grid (64, 2, 32).
__global__ __launch_bounds__(256) void transpose_v_kernel(
    const unsigned short* __restrict__ V, unsigned short* __restrict__ Vt) {
  __shared__ unsigned short tile[32][36];
  const int kt = blockIdx.x * 32;
  const int d0 = blockIdx.y * 32;
  const int bh = blockIdx.z;
  const int bb = bh >> 4, h = bh & 15;
  const int t = threadIdx.x;
  const int r = t >> 3, c4 = (t & 7) * 4;
  ushort4 v = *(const ushort4*)&V[((size_t)bb * 2048 + kt + r) * 1024 + h * 64 + d0 + c4];
  tile[c4 + 0][r] = v.x;
  tile[c4 + 1][r] = v.y;
  tile[c4 + 2][r] = v.z;
  tile[c4 + 3][r] = v.w;
  __syncthreads();
  ushort4 o;
  o.x = tile[r][c4 + 0];
  o.y = tile[r][c4 + 1];
  o.z = tile[r][c4 + 2];
  o.w = tile[r][c4 + 3];
  *(ushort4*)&Vt[((size_t)bh * 64 + d0 + r) * 2048 + kt + c4] = o;
}

// --------------------------------- layernorm -------------------------------
__global__ __launch_bounds__(256) void ln_kernel(
    const float* __restrict__ x, const float* __restrict__ g,
    const float* __restrict__ b, unsigned short* __restrict__ out) {
  const int row = blockIdx.x, t = threadIdx.x;
  const float4 v = ((const float4*)(x + (size_t)row * 1024))[t];
  float s = v.x + v.y + v.z + v.w;
  float s2 = v.x * v.x + v.y * v.y + v.z * v.z + v.w * v.w;
  for (int o = 32; o > 0; o >>= 1) {
    s += __shfl_xor(s, o, 64);
    s2 += __shfl_xor(s2, o, 64);
  }
  __shared__ float red[8];
  const int w = t >> 6;
  if ((t & 63) == 0) { red[w] = s; red[4 + w] = s2; }
  __syncthreads();
  s = red[0] + red[1] + red[2] + red[3];
  s2 = red[4] + red[5] + red[6] + red[7];
  const float mu = s * (1.f / 1024.f);
  const float var = s2 * (1.f / 1024.f) - mu * mu;
  const float rs = rsqrtf(var + 1e-5f);
  const float4 gg = ((const float4*)g)[t];
  const float4 bb = ((const float4*)b)[t];
  ushort4 o4;
  o4.x = f2bf((v.x - mu) * rs * gg.x + bb.x);
  o4.y = f2bf((v.y - mu) * rs * gg.y + bb.y);
  o4.z = f2bf((v.z - mu) * rs * gg.z + bb.z);
  o4.w = f2bf((v.w - mu) * rs * gg.w + bb.w);
  ((ushort4*)(out + (size_t)row * 1024))[t] = o4;
}

// ----------------------------------- GEMM ----------------------------------
// C = A[M][K](bf16) * Bt[N][K](bf16)^T with per-mode epilogue.
// 128x128 tile, BK=32, 256 thr (4 waves, 2x2 of 64x64), 16x16x32 MFMA.
enum { MODE_QKV = 0, MODE_RES = 1, MODE_GELU = 2 };

// Q pre-scale: (1/sqrt(64)) * log2(e) folded into Q so attention softmax
// runs in exp2 domain with no per-score multiply.
#define QSCALE 0.18033688011112043f

template <int MODE>
__global__ __launch_bounds__(256) void gemm_kernel(
    const unsigned short* __restrict__ A, const unsigned short* __restrict__ Bt,
    const float* __restrict__ bias0, const float* __restrict__ bias1,
    const float* __restrict__ bias2, const float* __restrict__ residual,
    void* __restrict__ out0, void* __restrict__ out1, void* __restrict__ out2,
    int M, int N, int K) {
  __shared__ __align__(16) unsigned short As[128 * 32];
  __shared__ __align__(16) unsigned short Bs[128 * 32];
  const int t = threadIdx.x;
  const int m0 = blockIdx.y * 128, n0 = blockIdx.x * 128;
  const int l = t & 63, w = t >> 6;
  const int wm = (w >> 1) * 64, wn = (w & 1) * 64;
  const int lr = l & 15, lq = l >> 4;

  f32x4 acc[4][4];
#pragma unroll
  for (int i = 0; i < 4; i++)
#pragma unroll
    for (int j = 0; j < 4; j++) {
      f32x4 z = {0.f, 0.f, 0.f, 0.f};
      acc[i][j] = z;
    }

  for (int k0 = 0; k0 < K; k0 += 32) {
    __syncthreads();
#pragma unroll
    for (int s = 0; s < 2; s++) {
      const int c = t + s * 256;
      const int row = c >> 2, c8 = (c & 3) * 8;
      async_copy16(&A[(size_t)(m0 + row) * K + k0 + c8], &As[c * 8]);
      async_copy16(&Bt[(size_t)(n0 + row) * K + k0 + c8], &Bs[c * 8]);
    }
    __syncthreads();
    bf16x8 af[4], bf[4];
#pragma unroll
    for (int mi = 0; mi < 4; mi++)
      af[mi] = ld_bf16x8(&As[(wm + mi * 16 + lr) * 32 + lq * 8]);
#pragma unroll
    for (int ni = 0; ni < 4; ni++)
      bf[ni] = ld_bf16x8(&Bs[(wn + ni * 16 + lr) * 32 + lq * 8]);
#pragma unroll
    for (int mi = 0; mi < 4; mi++)
#pragma unroll
      for (int ni = 0; ni < 4; ni++)
        acc[mi][ni] = __builtin_amdgcn_mfma_f32_16x16x32_bf16(
            af[mi], bf[ni], acc[mi][ni], 0, 0, 0);
  }

#pragma unroll
  for (int mi = 0; mi < 4; mi++) {
#pragma unroll
    for (int ni = 0; ni < 4; ni++) {
#pragma unroll
      for (int i = 0; i < 4; i++) {
        const int gm = m0 + wm + mi * 16 + lq * 4 + i;
        const int gn = n0 + wn + ni * 16 + lr;
        const float v = acc[mi][ni][i];
        if (MODE == MODE_QKV) {
          const int sel = gn >> 10, cn = gn & 1023;
          const float* bb = sel == 0 ? bias0 : (sel == 1 ? bias1 : bias2);
          unsigned short* dst =
              (unsigned short*)(sel == 0 ? out0 : (sel == 1 ? out1 : out2));
          float u = v + bb[cn];
          if (sel == 0) u *= QSCALE;  // fold softmax scale into Q
          dst[(size_t)gm * 1024 + cn] = f2bf(u);
        } else if (MODE == MODE_RES) {
          ((float*)out0)[(size_t)gm * N + gn] =
              v + bias0[gn] + residual[(size_t)gm * N + gn];
        } else {  // MODE_GELU, exact
          const float u = v + bias0[gn];
          const float ge = 0.5f * u * (1.f + erff(u * 0.70710678118654752f));
          ((unsigned short*)out0)[(size_t)gm * N + gn] = f2bf(ge);
        }
      }
    }
  }
}

// ------------------------------ flash attention ----------------------------
// grid (16 q-tiles of 128, 32 b*h). Q pre-scaled by QSCALE.
// Q/K bf16 [4096][1024]; Vt bf16 [32][64][2048]. Block: 128 queries,
// 4 waves x 32 q (2 subtiles of 16). Key tiles of 64. S^T scheme:
//   S^T[key][q] = mfma(kf, qf)  (C-layout: col=q -> softmax row = lane regs)
//   P[q][key] packs 4 consecutive keys/lane -> ds_write_b64 into Ps
//   O[q][d]  = mfma(pf, vf) with P as A-op, V^T as B-op.
// Ps aliases Qs (qf hoisted to regs before K-loop). LDS 36KB.
__global__ __launch_bounds__(256) void attn_kernel(
    const unsigned short* __restrict__ Q, const unsigned short* __restrict__ Kt,
    const unsigned short* __restrict__ Vt, unsigned short* __restrict__ O) {
  __shared__ __align__(16) unsigned short QPs[128 * 72];  // Qs then Ps
  __shared__ __align__(16) unsigned short Ks[64 * 72];
  __shared__ __align__(16) unsigned short Vs[64 * 72];
  const int qt = blockIdx.x;
  const int bh = blockIdx.y;
  const int bb = bh >> 4, h = bh & 15;
  const int t = threadIdx.x, l = t & 63, w = t >> 6;
  const int lr = l & 15, lq = l >> 4;
  const size_t rowBase = (size_t)bb * 2048;
  const int col0 = h * 64;

  // stage Q tile (128 x 64)
#pragma unroll
  for (int s = 0; s < 4; s++) {
    const int c = t + s * 256;
    const int r = c >> 3, c8 = (c & 7) * 8;
    *(uint4*)&QPs[r * 72 + c8] =
        *(const uint4*)&Q[(rowBase + qt * 128 + r) * 1024 + col0 + c8];
  }
  __syncthreads();
  bf16x8 qf[2][2];
#pragma unroll
  for (int s = 0; s < 2; s++)
#pragma unroll
    for (int kk = 0; kk < 2; kk++)
      qf[s][kk] = ld_bf16x8(&QPs[(w * 32 + s * 16 + lr) * 72 + kk * 32 + lq * 8]);
  // QPs LDS now dead as Q; reused as Ps below (first loop-top barrier guards).

  f32x4 oacc[2][4];
#pragma unroll
  for (int s = 0; s < 2; s++)
#pragma unroll
    for (int nt = 0; nt < 4; nt++) {
      f32x4 z = {0.f, 0.f, 0.f, 0.f};
      oacc[s][nt] = z;
    }
  float mi_[2] = {-1e30f, -1e30f};
  float lp[2] = {0.f, 0.f};

  for (int kt = 0; kt < 2048; kt += 64) {
    __syncthreads();
#pragma unroll
    for (int s = 0; s < 2; s++) {
      const int c = t + s * 256;
      const int r = c >> 3, c8 = (c & 7) * 8;
      *(uint4*)&Ks[r * 72 + c8] =
          *(const uint4*)&Kt[(rowBase + kt + r) * 1024 + col0 + c8];
      *(uint4*)&Vs[r * 72 + c8] =
          *(const uint4*)&Vt[((size_t)bh * 64 + r) * 2048 + kt + c8];
    }
    __syncthreads();

    // S^T[key][q]: 4 key-tiles x 2 q-subtiles; kf shared across subtiles.
    f32x4 st[2][4];
#pragma unroll
    for (int s = 0; s < 2; s++)
#pragma unroll
      for (int nt = 0; nt < 4; nt++) {
        f32x4 z = {0.f, 0.f, 0.f, 0.f};
        st[s][nt] = z;
      }
#pragma unroll
    for (int nt = 0; nt < 4; nt++)
#pragma unroll
      for (int kk = 0; kk < 2; kk++) {
        bf16x8 kf = ld_bf16x8(&Ks[(nt * 16 + lr) * 72 + kk * 32 + lq * 8]);
        st[0][nt] = __builtin_amdgcn_mfma_f32_16x16x32_bf16(kf, qf[0][kk], st[0][nt], 0, 0, 0);
        st[1][nt] = __builtin_amdgcn_mfma_f32_16x16x32_bf16(kf, qf[1][kk], st[1][nt], 0, 0, 0);
      }

    // online softmax (exp2 domain; scores pre-scaled via Q).
    // Lane holds, for its query q=lr (per subtile), keys nt*16+lq*4+i.
#pragma unroll
    for (int s = 0; s < 2; s++) {
      float mx = st[s][0][0];
#pragma unroll
      for (int nt = 0; nt < 4; nt++)
#pragma unroll
        for (int i = 0; i < 4; i++) mx = fmaxf(mx, st[s][nt][i]);
      mx = fmaxf(mx, __shfl_xor(mx, 16, 64));
      mx = fmaxf(mx, __shfl_xor(mx, 32, 64));
      const float mnew = fmaxf(mi_[s], mx);
      const float alpha = exp2f(mi_[s] - mnew);
      mi_[s] = mnew;
      float rsum = 0.f;
#pragma unroll
      for (int nt = 0; nt < 4; nt++)
#pragma unroll
        for (int i = 0; i < 4; i++) {
          const float p = exp2f(st[s][nt][i] - mnew);
          st[s][nt][i] = p;
          rsum += p;
        }
      lp[s] = lp[s] * alpha + rsum;  // per-lane partial (16 of 64 keys)
#pragma unroll
      for (int nt = 0; nt < 4; nt++) oacc[s][nt] *= alpha;
    }

    // P[q][key] -> Ps: lane has 4 consecutive keys -> pack 2 dwords, b64 write.
    // Wave-private rows [w*32, w*32+32); truncation pack (P in [0,1]).
#pragma unroll
    for (int s = 0; s < 2; s++)
#pragma unroll
      for (int nt = 0; nt < 4; nt++) {
        uint2 pk;
        pk.x = __builtin_amdgcn_perm(fbits(st[s][nt][1]), fbits(st[s][nt][0]), 0x07060302u);
        pk.y = __builtin_amdgcn_perm(fbits(st[s][nt][3]), fbits(st[s][nt][2]), 0x07060302u);
        *(uint2*)&QPs[(w * 32 + s * 16 + lr) * 72 + nt * 16 + lq * 4] = pk;
      }

    // O[q][d] += P (A-op) * V (B-op from V^T rows).
#pragma unroll
    for (int kb = 0; kb < 2; kb++) {
      bf16x8 pf0 = ld_bf16x8(&QPs[(w * 32 + lr) * 72 + kb * 32 + lq * 8]);
      bf16x8 pf1 = ld_bf16x8(&QPs[(w * 32 + 16 + lr) * 72 + kb * 32 + lq * 8]);
#pragma unroll
      for (int nt = 0; nt < 4; nt++) {
        bf16x8 vf = ld_bf16x8(&Vs[(nt * 16 + lr) * 72 + kb * 32 + lq * 8]);
        oacc[0][nt] = __builtin_amdgcn_mfma_f32_16x16x32_bf16(pf0, vf, oacc[0][nt], 0, 0, 0);
        oacc[1][nt] = __builtin_amdgcn_mfma_f32_16x16x32_bf16(pf1, vf, oacc[1][nt], 0, 0, 0);
      }
    }
  }

#pragma unroll
  for (int s = 0; s < 2; s++) {
    float li = lp[s];
    li += __shfl_xor(li, 16, 64);
    li += __shfl_xor(li, 32, 64);
    const float inv = 1.f / li;
#pragma unroll
    for (int nt = 0; nt < 4; nt++)
#pragma unroll
      for (int i = 0; i < 4; i++) {
        const size_t orow = rowBase + qt * 128 + w * 32 + s * 16 + lq * 4 + i;
        const int ocol = col0 + nt * 16 + lr;
        O[orow * 1024 + ocol] = f2bf(oacc[s][nt][i] * inv);
      }
  }
}

// --------------------------------- launcher --------------------------------
extern "C" void kernel_launch(void* const* d_in, const int* in_sizes, int n_in,
                              void* d_out, int out_size, void* d_ws, size_t ws_size,
                              hipStream_t stream) {
  const float* x    = (const float*)d_in[0];
  const float* Wq   = (const float*)d_in[1];
  const float* bq   = (const float*)d_in[2];
  const float* Wk   = (const float*)d_in[3];
  const float* bk   = (const float*)d_in[4];
  const float* Wv   = (const float*)d_in[5];
  const float* bv   = (const float*)d_in[6];
  const float* Wo   = (const float*)d_in[7];
  const float* bo   = (const float*)d_in[8];
  const float* W1   = (const float*)d_in[9];
  const float* b1   = (const float*)d_in[10];
  const float* W2   = (const float*)d_in[11];
  const float* b2   = (const float*)d_in[12];
  const float* ln1g = (const float*)d_in[13];
  const float* ln1b = (const float*)d_in[14];
  const float* ln2g = (const float*)d_in[15];
  const float* ln2b = (const float*)d_in[16];

  char* ws = (char*)d_ws;
  const size_t MB = 1024ull * 1024ull;
  unsigned short* WqT = (unsigned short*)(ws + 0 * MB);   // 2MB  \  contiguous:
  unsigned short* WkT = (unsigned short*)(ws + 2 * MB);   // 2MB   } fused QKV B
  unsigned short* WvT = (unsigned short*)(ws + 4 * MB);   // 2MB  /  [3072][1024]
  unsigned short* WoT = (unsigned short*)(ws + 6 * MB);   // 2MB
  unsigned short* W1T = (unsigned short*)(ws + 8 * MB);   // 8MB [4096][1024]
  unsigned short* W2T = (unsigned short*)(ws + 16 * MB);  // 8MB [1024][4096]
  unsigned short* xn  = (unsigned short*)(ws + 24 * MB);  // 8MB
  unsigned short* Qb  = (unsigned short*)(ws + 32 * MB);  // 8MB (pre-scaled)
  unsigned short* Kb  = (unsigned short*)(ws + 40 * MB);  // 8MB
  unsigned short* Vb  = (unsigned short*)(ws + 48 * MB);  // 8MB
  unsigned short* Ob  = (unsigned short*)(ws + 56 * MB);  // 8MB
  float*          x1  = (float*)(ws + 64 * MB);           // 16MB
  unsigned short* h2  = (unsigned short*)(ws + 80 * MB);  // 8MB  (total 88MB)
  // aliases (regions dead by the time they're reused):
  unsigned short* VtG = (unsigned short*)(ws + 24 * MB);  // 8MB alias xn
  unsigned short* Hb  = (unsigned short*)(ws + 24 * MB);  // 32MB alias xn/Q/K/V

  const dim3 blk(256);

  transpose_cast_kernel<<<dim3(32, 32), blk, 0, stream>>>(Wq, WqT, 1024, 1024);
  transpose_cast_kernel<<<dim3(32, 32), blk, 0, stream>>>(Wk, WkT, 1024, 1024);
  transpose_cast_kernel<<<dim3(32, 32), blk, 0, stream>>>(Wv, WvT, 1024, 1024);
  transpose_cast_kernel<<<dim3(32, 32), blk, 0, stream>>>(Wo, WoT, 1024, 1024);
  transpose_cast_kernel<<<dim3(128, 32), blk, 0, stream>>>(W1, W1T, 4096, 1024);
  transpose_cast_kernel<<<dim3(32, 128), blk, 0, stream>>>(W2, W2T, 1024, 4096);

  ln_kernel<<<4096, blk, 0, stream>>>(x, ln1g, ln1b, xn);

  gemm_kernel<MODE_QKV><<<dim3(3072 / 128, 4096 / 128), blk, 0, stream>>>(
      xn, WqT, bq, bk, bv, nullptr, Qb, Kb, Vb, 4096, 3072, 1024);

  transpose_v_kernel<<<dim3(64, 2, 32), blk, 0, stream>>>(Vb, VtG);

  attn_kernel<<<dim3(16, 32), blk, 0, stream>>>(Qb, Kb, VtG, Ob);

  gemm_kernel<MODE_RES><<<dim3(1024 / 128, 4096 / 128), blk, 0, stream>>>(
      Ob, WoT, bo, nullptr, nullptr, x, x1, nullptr, nullptr, 4096, 1024, 1024);

  ln_kernel<<<4096, blk, 0, stream>>>(x1, ln2g, ln2b, h2);

  gemm_kernel<MODE_GELU><<<dim3(4096 / 128, 4096 / 128), blk, 0, stream>>>(
      h2, W1T, b1, nullptr, nullptr, nullptr, Hb, nullptr, nullptr, 4096, 4096, 1024);

  gemm_kernel<MODE_RES><<<dim3(1024 / 128, 4096 / 128), blk, 0, stream>>>(
      Hb, W2T, b2, nullptr, nullptr, x1, (float*)d_out, nullptr, nullptr, 4096, 1024, 4096);
}

// Round 4
// 425.474 us; speedup vs baseline: 1.2751x; 1.0699x over previous
//
#include <hip/hip_runtime.h>
#include <hip/hip_bf16.h>
#include <math.h>

// ---------------------------------------------------------------------------
// Transformer block (B=2, T=2048, C=1024, NH=16, hd=64), fp32 in/out.
// R4 changes vs R3 (GEMM restructure; attn unchanged):
//  - BK=64 (two packed 32-k LDS half-tiles: keeps global_load_lds lane
//    contiguity per half AND stride-32 frag reads). Halves barrier drains.
//  - Templated tiles <BM,BN>: 128x128 for QKV/MLP1; 64x128 for proj/MLP2
//    (grid 256 -> 512 blocks = 2/CU on the grid-starved shapes).
// ---------------------------------------------------------------------------

typedef __bf16 bf16x8 __attribute__((ext_vector_type(8)));
typedef float f32x4 __attribute__((ext_vector_type(4)));

__device__ __forceinline__ unsigned short f2bf(float f) {
  union { float f; unsigned int u; } v; v.f = f;
  unsigned int u = v.u;
  unsigned int r = (u + 0x7fffu + ((u >> 16) & 1u)) >> 16;  // RNE
  return (unsigned short)r;
}

__device__ __forceinline__ unsigned int fbits(float f) {
  union { float f; unsigned int u; } v; v.f = f;
  return v.u;
}

__device__ __forceinline__ bf16x8 ld_bf16x8(const unsigned short* p) {
  union { uint4 u; bf16x8 v; } x;
  x.u = *(const uint4*)p;
  return x.v;
}

// async 16B global->LDS (DMA). LDS dest is wave-uniform base + lane*16.
__device__ __forceinline__ void async_copy16(const void* g, void* l) {
  __builtin_amdgcn_global_load_lds(
      (const __attribute__((address_space(1))) void*)g,
      (__attribute__((address_space(3))) void*)l, 16, 0, 0);
}

// --------------------------- weight transpose+cast -------------------------
__global__ __launch_bounds__(256) void transpose_cast_kernel(
    const float* __restrict__ W, unsigned short* __restrict__ Wt, int N, int K) {
  __shared__ unsigned short tile[32][33];
  const int n0 = blockIdx.x * 32, k0 = blockIdx.y * 32;
  const int t = threadIdx.x;
  const int r = t >> 3, cq = (t & 7) * 4;
  float4 v = *(const float4*)&W[(size_t)(k0 + r) * N + n0 + cq];
  tile[cq + 0][r] = f2bf(v.x);
  tile[cq + 1][r] = f2bf(v.y);
  tile[cq + 2][r] = f2bf(v.z);
  tile[cq + 3][r] = f2bf(v.w);
  __syncthreads();
  ushort4 o;
  o.x = tile[r][cq + 0];
  o.y = tile[r][cq + 1];
  o.z = tile[r][cq + 2];
  o.w = tile[r][cq + 3];
  *(ushort4*)&Wt[(size_t)(n0 + r) * K + k0 + cq] = o;
}

// ------------------------------- V transpose -------------------------------
// V bf16 [4096][1024] -> Vt bf16 [32 bh][64 d][2048 k]. grid (64, 2, 32).
__global__ __launch_bounds__(256) void transpose_v_kernel(
    const unsigned short* __restrict__ V, unsigned short* __restrict__ Vt) {
  __shared__ unsigned short tile[32][36];
  const int kt = blockIdx.x * 32;
  const int d0 = blockIdx.y * 32;
  const int bh = blockIdx.z;
  const int bb = bh >> 4, h = bh & 15;
  const int t = threadIdx.x;
  const int r = t >> 3, c4 = (t & 7) * 4;
  ushort4 v = *(const ushort4*)&V[((size_t)bb * 2048 + kt + r) * 1024 + h * 64 + d0 + c4];
  tile[c4 + 0][r] = v.x;
  tile[c4 + 1][r] = v.y;
  tile[c4 + 2][r] = v.z;
  tile[c4 + 3][r] = v.w;
  __syncthreads();
  ushort4 o;
  o.x = tile[r][c4 + 0];
  o.y = tile[r][c4 + 1];
  o.z = tile[r][c4 + 2];
  o.w = tile[r][c4 + 3];
  *(ushort4*)&Vt[((size_t)bh * 64 + d0 + r) * 2048 + kt + c4] = o;
}

// --------------------------------- layernorm -------------------------------
__global__ __launch_bounds__(256) void ln_kernel(
    const float* __restrict__ x, const float* __restrict__ g,
    const float* __restrict__ b, unsigned short* __restrict__ out) {
  const int row = blockIdx.x, t = threadIdx.x;
  const float4 v = ((const float4*)(x + (size_t)row * 1024))[t];
  float s = v.x + v.y + v.z + v.w;
  float s2 = v.x * v.x + v.y * v.y + v.z * v.z + v.w * v.w;
  for (int o = 32; o > 0; o >>= 1) {
    s += __shfl_xor(s, o, 64);
    s2 += __shfl_xor(s2, o, 64);
  }
  __shared__ float red[8];
  const int w = t >> 6;
  if ((t & 63) == 0) { red[w] = s; red[4 + w] = s2; }
  __syncthreads();
  s = red[0] + red[1] + red[2] + red[3];
  s2 = red[4] + red[5] + red[6] + red[7];
  const float mu = s * (1.f / 1024.f);
  const float var = s2 * (1.f / 1024.f) - mu * mu;
  const float rs = rsqrtf(var + 1e-5f);
  const float4 gg = ((const float4*)g)[t];
  const float4 bb = ((const float4*)b)[t];
  ushort4 o4;
  o4.x = f2bf((v.x - mu) * rs * gg.x + bb.x);
  o4.y = f2bf((v.y - mu) * rs * gg.y + bb.y);
  o4.z = f2bf((v.z - mu) * rs * gg.z + bb.z);
  o4.w = f2bf((v.w - mu) * rs * gg.w + bb.w);
  ((ushort4*)(out + (size_t)row * 1024))[t] = o4;
}

// ----------------------------------- GEMM ----------------------------------
// C = A[M][K](bf16) * Bt[N][K](bf16)^T, BK=64 via two packed 32-k half-tiles.
// 256 thr, 4 waves 2x2; wave tile (BM/2)x(BN/2); 16x16x32 MFMA.
enum { MODE_QKV = 0, MODE_RES = 1, MODE_GELU = 2 };

// (1/sqrt(64)) * log2(e) folded into Q at QKV epilogue (exp2-domain softmax).
#define QSCALE 0.18033688011112043f

template <int BM, int BN, int MODE>
__global__ __launch_bounds__(256) void gemm_kernel(
    const unsigned short* __restrict__ A, const unsigned short* __restrict__ Bt,
    const float* __restrict__ bias0, const float* __restrict__ bias1,
    const float* __restrict__ bias2, const float* __restrict__ residual,
    void* __restrict__ out0, void* __restrict__ out1, void* __restrict__ out2,
    int M, int N, int K) {
  constexpr int MI = BM / 32;  // m-subtiles per wave
  constexpr int NI = BN / 32;  // n-subtiles per wave
  __shared__ __align__(16) unsigned short As[2][BM * 32];
  __shared__ __align__(16) unsigned short Bs[2][BN * 32];
  const int t = threadIdx.x;
  const int m0 = blockIdx.y * BM, n0 = blockIdx.x * BN;
  const int l = t & 63, w = t >> 6;
  const int wm = (w >> 1) * (BM / 2), wn = (w & 1) * (BN / 2);
  const int lr = l & 15, lq = l >> 4;

  f32x4 acc[MI][NI];
#pragma unroll
  for (int i = 0; i < MI; i++)
#pragma unroll
    for (int j = 0; j < NI; j++) {
      f32x4 z = {0.f, 0.f, 0.f, 0.f};
      acc[i][j] = z;
    }

  for (int k0 = 0; k0 < K; k0 += 64) {
    __syncthreads();
#pragma unroll
    for (int h = 0; h < 2; h++)
#pragma unroll
      for (int s = 0; s < BM / 64; s++) {
        const int c = t + s * 256;
        const int row = c >> 2, k8 = (c & 3) * 8;
        async_copy16(&A[(size_t)(m0 + row) * K + k0 + h * 32 + k8],
                     &As[h][c * 8]);
      }
#pragma unroll
    for (int h = 0; h < 2; h++)
#pragma unroll
      for (int s = 0; s < BN / 64; s++) {
        const int c = t + s * 256;
        const int row = c >> 2, k8 = (c & 3) * 8;
        async_copy16(&Bt[(size_t)(n0 + row) * K + k0 + h * 32 + k8],
                     &Bs[h][c * 8]);
      }
    __syncthreads();
#pragma unroll
    for (int kk = 0; kk < 2; kk++) {
      bf16x8 af[MI], bf[NI];
#pragma unroll
      for (int mi = 0; mi < MI; mi++)
        af[mi] = ld_bf16x8(&As[kk][(wm + mi * 16 + lr) * 32 + lq * 8]);
#pragma unroll
      for (int ni = 0; ni < NI; ni++)
        bf[ni] = ld_bf16x8(&Bs[kk][(wn + ni * 16 + lr) * 32 + lq * 8]);
#pragma unroll
      for (int mi = 0; mi < MI; mi++)
#pragma unroll
        for (int ni = 0; ni < NI; ni++)
          acc[mi][ni] = __builtin_amdgcn_mfma_f32_16x16x32_bf16(
              af[mi], bf[ni], acc[mi][ni], 0, 0, 0);
    }
  }

#pragma unroll
  for (int mi = 0; mi < MI; mi++) {
#pragma unroll
    for (int ni = 0; ni < NI; ni++) {
#pragma unroll
      for (int i = 0; i < 4; i++) {
        const int gm = m0 + wm + mi * 16 + lq * 4 + i;
        const int gn = n0 + wn + ni * 16 + lr;
        const float v = acc[mi][ni][i];
        if (MODE == MODE_QKV) {
          const int sel = gn >> 10, cn = gn & 1023;
          const float* bb = sel == 0 ? bias0 : (sel == 1 ? bias1 : bias2);
          unsigned short* dst =
              (unsigned short*)(sel == 0 ? out0 : (sel == 1 ? out1 : out2));
          float u = v + bb[cn];
          if (sel == 0) u *= QSCALE;  // fold softmax scale into Q
          dst[(size_t)gm * 1024 + cn] = f2bf(u);
        } else if (MODE == MODE_RES) {
          ((float*)out0)[(size_t)gm * N + gn] =
              v + bias0[gn] + residual[(size_t)gm * N + gn];
        } else {  // MODE_GELU, exact
          const float u = v + bias0[gn];
          const float ge = 0.5f * u * (1.f + erff(u * 0.70710678118654752f));
          ((unsigned short*)out0)[(size_t)gm * N + gn] = f2bf(ge);
        }
      }
    }
  }
}

// ------------------------------ flash attention ----------------------------
// grid (16 q-tiles of 128, 32 b*h). Q pre-scaled by QSCALE. S^T scheme.
__global__ __launch_bounds__(256) void attn_kernel(
    const unsigned short* __restrict__ Q, const unsigned short* __restrict__ Kt,
    const unsigned short* __restrict__ Vt, unsigned short* __restrict__ O) {
  __shared__ __align__(16) unsigned short QPs[128 * 72];  // Qs then Ps
  __shared__ __align__(16) unsigned short Ks[64 * 72];
  __shared__ __align__(16) unsigned short Vs[64 * 72];
  const int qt = blockIdx.x;
  const int bh = blockIdx.y;
  const int bb = bh >> 4, h = bh & 15;
  const int t = threadIdx.x, l = t & 63, w = t >> 6;
  const int lr = l & 15, lq = l >> 4;
  const size_t rowBase = (size_t)bb * 2048;
  const int col0 = h * 64;

  // stage Q tile (128 x 64)
#pragma unroll
  for (int s = 0; s < 4; s++) {
    const int c = t + s * 256;
    const int r = c >> 3, c8 = (c & 7) * 8;
    *(uint4*)&QPs[r * 72 + c8] =
        *(const uint4*)&Q[(rowBase + qt * 128 + r) * 1024 + col0 + c8];
  }
  __syncthreads();
  bf16x8 qf[2][2];
#pragma unroll
  for (int s = 0; s < 2; s++)
#pragma unroll
    for (int kk = 0; kk < 2; kk++)
      qf[s][kk] = ld_bf16x8(&QPs[(w * 32 + s * 16 + lr) * 72 + kk * 32 + lq * 8]);
  // QPs now dead as Q; reused as Ps (loop-top barrier guards).

  f32x4 oacc[2][4];
#pragma unroll
  for (int s = 0; s < 2; s++)
#pragma unroll
    for (int nt = 0; nt < 4; nt++) {
      f32x4 z = {0.f, 0.f, 0.f, 0.f};
      oacc[s][nt] = z;
    }
  float mi_[2] = {-1e30f, -1e30f};
  float lp[2] = {0.f, 0.f};

  for (int kt = 0; kt < 2048; kt += 64) {
    __syncthreads();
#pragma unroll
    for (int s = 0; s < 2; s++) {
      const int c = t + s * 256;
      const int r = c >> 3, c8 = (c & 7) * 8;
      *(uint4*)&Ks[r * 72 + c8] =
          *(const uint4*)&Kt[(rowBase + kt + r) * 1024 + col0 + c8];
      *(uint4*)&Vs[r * 72 + c8] =
          *(const uint4*)&Vt[((size_t)bh * 64 + r) * 2048 + kt + c8];
    }
    __syncthreads();

    // S^T[key][q]: kf shared across the two q-subtiles.
    f32x4 st[2][4];
#pragma unroll
    for (int s = 0; s < 2; s++)
#pragma unroll
      for (int nt = 0; nt < 4; nt++) {
        f32x4 z = {0.f, 0.f, 0.f, 0.f};
        st[s][nt] = z;
      }
#pragma unroll
    for (int nt = 0; nt < 4; nt++)
#pragma unroll
      for (int kk = 0; kk < 2; kk++) {
        bf16x8 kf = ld_bf16x8(&Ks[(nt * 16 + lr) * 72 + kk * 32 + lq * 8]);
        st[0][nt] = __builtin_amdgcn_mfma_f32_16x16x32_bf16(kf, qf[0][kk], st[0][nt], 0, 0, 0);
        st[1][nt] = __builtin_amdgcn_mfma_f32_16x16x32_bf16(kf, qf[1][kk], st[1][nt], 0, 0, 0);
      }

    // online softmax (exp2 domain); lane's query q=lr per subtile.
#pragma unroll
    for (int s = 0; s < 2; s++) {
      float mx = st[s][0][0];
#pragma unroll
      for (int nt = 0; nt < 4; nt++)
#pragma unroll
        for (int i = 0; i < 4; i++) mx = fmaxf(mx, st[s][nt][i]);
      mx = fmaxf(mx, __shfl_xor(mx, 16, 64));
      mx = fmaxf(mx, __shfl_xor(mx, 32, 64));
      const float mnew = fmaxf(mi_[s], mx);
      const float alpha = exp2f(mi_[s] - mnew);
      mi_[s] = mnew;
      float rsum = 0.f;
#pragma unroll
      for (int nt = 0; nt < 4; nt++)
#pragma unroll
        for (int i = 0; i < 4; i++) {
          const float p = exp2f(st[s][nt][i] - mnew);
          st[s][nt][i] = p;
          rsum += p;
        }
      lp[s] = lp[s] * alpha + rsum;
#pragma unroll
      for (int nt = 0; nt < 4; nt++) oacc[s][nt] *= alpha;
    }

    // P[q][key] -> Ps (b64 writes, bf16 truncation pack).
#pragma unroll
    for (int s = 0; s < 2; s++)
#pragma unroll
      for (int nt = 0; nt < 4; nt++) {
        uint2 pk;
        pk.x = __builtin_amdgcn_perm(fbits(st[s][nt][1]), fbits(st[s][nt][0]), 0x07060302u);
        pk.y = __builtin_amdgcn_perm(fbits(st[s][nt][3]), fbits(st[s][nt][2]), 0x07060302u);
        *(uint2*)&QPs[(w * 32 + s * 16 + lr) * 72 + nt * 16 + lq * 4] = pk;
      }

    // O += P (A-op) * V (B-op from V^T rows).
#pragma unroll
    for (int kb = 0; kb < 2; kb++) {
      bf16x8 pf0 = ld_bf16x8(&QPs[(w * 32 + lr) * 72 + kb * 32 + lq * 8]);
      bf16x8 pf1 = ld_bf16x8(&QPs[(w * 32 + 16 + lr) * 72 + kb * 32 + lq * 8]);
#pragma unroll
      for (int nt = 0; nt < 4; nt++) {
        bf16x8 vf = ld_bf16x8(&Vs[(nt * 16 + lr) * 72 + kb * 32 + lq * 8]);
        oacc[0][nt] = __builtin_amdgcn_mfma_f32_16x16x32_bf16(pf0, vf, oacc[0][nt], 0, 0, 0);
        oacc[1][nt] = __builtin_amdgcn_mfma_f32_16x16x32_bf16(pf1, vf, oacc[1][nt], 0, 0, 0);
      }
    }
  }

#pragma unroll
  for (int s = 0; s < 2; s++) {
    float li = lp[s];
    li += __shfl_xor(li, 16, 64);
    li += __shfl_xor(li, 32, 64);
    const float inv = 1.f / li;
#pragma unroll
    for (int nt = 0; nt < 4; nt++)
#pragma unroll
      for (int i = 0; i < 4; i++) {
        const size_t orow = rowBase + qt * 128 + w * 32 + s * 16 + lq * 4 + i;
        const int ocol = col0 + nt * 16 + lr;
        O[orow * 1024 + ocol] = f2bf(oacc[s][nt][i] * inv);
      }
  }
}

// --------------------------------- launcher --------------------------------
extern "C" void kernel_launch(void* const* d_in, const int* in_sizes, int n_in,
                              void* d_out, int out_size, void* d_ws, size_t ws_size,
                              hipStream_t stream) {
  const float* x    = (const float*)d_in[0];
  const float* Wq   = (const float*)d_in[1];
  const float* bq   = (const float*)d_in[2];
  const float* Wk   = (const float*)d_in[3];
  const float* bk   = (const float*)d_in[4];
  const float* Wv   = (const float*)d_in[5];
  const float* bv   = (const float*)d_in[6];
  const float* Wo   = (const float*)d_in[7];
  const float* bo   = (const float*)d_in[8];
  const float* W1   = (const float*)d_in[9];
  const float* b1   = (const float*)d_in[10];
  const float* W2   = (const float*)d_in[11];
  const float* b2   = (const float*)d_in[12];
  const float* ln1g = (const float*)d_in[13];
  const float* ln1b = (const float*)d_in[14];
  const float* ln2g = (const float*)d_in[15];
  const float* ln2b = (const float*)d_in[16];

  char* ws = (char*)d_ws;
  const size_t MB = 1024ull * 1024ull;
  unsigned short* WqT = (unsigned short*)(ws + 0 * MB);   // 2MB  \  contiguous:
  unsigned short* WkT = (unsigned short*)(ws + 2 * MB);   // 2MB   } fused QKV B
  unsigned short* WvT = (unsigned short*)(ws + 4 * MB);   // 2MB  /  [3072][1024]
  unsigned short* WoT = (unsigned short*)(ws + 6 * MB);   // 2MB
  unsigned short* W1T = (unsigned short*)(ws + 8 * MB);   // 8MB [4096][1024]
  unsigned short* W2T = (unsigned short*)(ws + 16 * MB);  // 8MB [1024][4096]
  unsigned short* xn  = (unsigned short*)(ws + 24 * MB);  // 8MB
  unsigned short* Qb  = (unsigned short*)(ws + 32 * MB);  // 8MB (pre-scaled)
  unsigned short* Kb  = (unsigned short*)(ws + 40 * MB);  // 8MB
  unsigned short* Vb  = (unsigned short*)(ws + 48 * MB);  // 8MB
  unsigned short* Ob  = (unsigned short*)(ws + 56 * MB);  // 8MB
  float*          x1  = (float*)(ws + 64 * MB);           // 16MB
  unsigned short* h2  = (unsigned short*)(ws + 80 * MB);  // 8MB  (total 88MB)
  // aliases (dead regions reused):
  unsigned short* VtG = (unsigned short*)(ws + 24 * MB);  // 8MB alias xn
  unsigned short* Hb  = (unsigned short*)(ws + 24 * MB);  // 32MB alias xn/Q/K/V

  const dim3 blk(256);

  transpose_cast_kernel<<<dim3(32, 32), blk, 0, stream>>>(Wq, WqT, 1024, 1024);
  transpose_cast_kernel<<<dim3(32, 32), blk, 0, stream>>>(Wk, WkT, 1024, 1024);
  transpose_cast_kernel<<<dim3(32, 32), blk, 0, stream>>>(Wv, WvT, 1024, 1024);
  transpose_cast_kernel<<<dim3(32, 32), blk, 0, stream>>>(Wo, WoT, 1024, 1024);
  transpose_cast_kernel<<<dim3(128, 32), blk, 0, stream>>>(W1, W1T, 4096, 1024);
  transpose_cast_kernel<<<dim3(32, 128), blk, 0, stream>>>(W2, W2T, 1024, 4096);

  ln_kernel<<<4096, blk, 0, stream>>>(x, ln1g, ln1b, xn);

  gemm_kernel<128, 128, MODE_QKV><<<dim3(24, 32), blk, 0, stream>>>(
      xn, WqT, bq, bk, bv, nullptr, Qb, Kb, Vb, 4096, 3072, 1024);

  transpose_v_kernel<<<dim3(64, 2, 32), blk, 0, stream>>>(Vb, VtG);

  attn_kernel<<<dim3(16, 32), blk, 0, stream>>>(Qb, Kb, VtG, Ob);

  gemm_kernel<64, 128, MODE_RES><<<dim3(8, 64), blk, 0, stream>>>(
      Ob, WoT, bo, nullptr, nullptr, x, x1, nullptr, nullptr, 4096, 1024, 1024);

  ln_kernel<<<4096, blk, 0, stream>>>(x1, ln2g, ln2b, h2);

  gemm_kernel<128, 128, MODE_GELU><<<dim3(32, 32), blk, 0, stream>>>(
      h2, W1T, b1, nullptr, nullptr, nullptr, Hb, nullptr, nullptr, 4096, 4096, 1024);

  gemm_kernel<64, 128, MODE_RES><<<dim3(8, 64), blk, 0, stream>>>(
      Hb, W2T, b2, nullptr, nullptr, x1, (float*)d_out, nullptr, nullptr, 4096, 1024, 4096);
}

// Round 5
// 424.695 us; speedup vs baseline: 1.2774x; 1.0018x over previous
//
#include <hip/hip_runtime.h>
#include <hip/hip_bf16.h>
#include <math.h>

// ---------------------------------------------------------------------------
// Transformer block (B=2, T=2048, C=1024, NH=16, hd=64), fp32 in/out.
// R5 changes vs R4:
//  - GEMM: XCD-aware tile swizzle (1D grid; xcd=bid&7 owns an M-stripe,
//    n-fastest inner) -> A-tile L2-resident per XCD, B-window L3-shared.
//  - Attention: q-tile 128 -> 64 (grid 512 -> 1024 blocks, LDS 36 -> 27KB;
//    4 blocks/CU co-resident instead of 2) to fill barrier drains via TLP.
// ---------------------------------------------------------------------------

typedef __bf16 bf16x8 __attribute__((ext_vector_type(8)));
typedef float f32x4 __attribute__((ext_vector_type(4)));

__device__ __forceinline__ unsigned short f2bf(float f) {
  union { float f; unsigned int u; } v; v.f = f;
  unsigned int u = v.u;
  unsigned int r = (u + 0x7fffu + ((u >> 16) & 1u)) >> 16;  // RNE
  return (unsigned short)r;
}

__device__ __forceinline__ unsigned int fbits(float f) {
  union { float f; unsigned int u; } v; v.f = f;
  return v.u;
}

__device__ __forceinline__ bf16x8 ld_bf16x8(const unsigned short* p) {
  union { uint4 u; bf16x8 v; } x;
  x.u = *(const uint4*)p;
  return x.v;
}

// async 16B global->LDS (DMA). LDS dest is wave-uniform base + lane*16.
__device__ __forceinline__ void async_copy16(const void* g, void* l) {
  __builtin_amdgcn_global_load_lds(
      (const __attribute__((address_space(1))) void*)g,
      (__attribute__((address_space(3))) void*)l, 16, 0, 0);
}

// --------------------------- weight transpose+cast -------------------------
__global__ __launch_bounds__(256) void transpose_cast_kernel(
    const float* __restrict__ W, unsigned short* __restrict__ Wt, int N, int K) {
  __shared__ unsigned short tile[32][33];
  const int n0 = blockIdx.x * 32, k0 = blockIdx.y * 32;
  const int t = threadIdx.x;
  const int r = t >> 3, cq = (t & 7) * 4;
  float4 v = *(const float4*)&W[(size_t)(k0 + r) * N + n0 + cq];
  tile[cq + 0][r] = f2bf(v.x);
  tile[cq + 1][r] = f2bf(v.y);
  tile[cq + 2][r] = f2bf(v.z);
  tile[cq + 3][r] = f2bf(v.w);
  __syncthreads();
  ushort4 o;
  o.x = tile[r][cq + 0];
  o.y = tile[r][cq + 1];
  o.z = tile[r][cq + 2];
  o.w = tile[r][cq + 3];
  *(ushort4*)&Wt[(size_t)(n0 + r) * K + k0 + cq] = o;
}

// ------------------------------- V transpose -------------------------------
// V bf16 [4096][1024] -> Vt bf16 [32 bh][64 d][2048 k]. grid (64, 2, 32).
__global__ __launch_bounds__(256) void transpose_v_kernel(
    const unsigned short* __restrict__ V, unsigned short* __restrict__ Vt) {
  __shared__ unsigned short tile[32][36];
  const int kt = blockIdx.x * 32;
  const int d0 = blockIdx.y * 32;
  const int bh = blockIdx.z;
  const int bb = bh >> 4, h = bh & 15;
  const int t = threadIdx.x;
  const int r = t >> 3, c4 = (t & 7) * 4;
  ushort4 v = *(const ushort4*)&V[((size_t)bb * 2048 + kt + r) * 1024 + h * 64 + d0 + c4];
  tile[c4 + 0][r] = v.x;
  tile[c4 + 1][r] = v.y;
  tile[c4 + 2][r] = v.z;
  tile[c4 + 3][r] = v.w;
  __syncthreads();
  ushort4 o;
  o.x = tile[r][c4 + 0];
  o.y = tile[r][c4 + 1];
  o.z = tile[r][c4 + 2];
  o.w = tile[r][c4 + 3];
  *(ushort4*)&Vt[((size_t)bh * 64 + d0 + r) * 2048 + kt + c4] = o;
}

// --------------------------------- layernorm -------------------------------
__global__ __launch_bounds__(256) void ln_kernel(
    const float* __restrict__ x, const float* __restrict__ g,
    const float* __restrict__ b, unsigned short* __restrict__ out) {
  const int row = blockIdx.x, t = threadIdx.x;
  const float4 v = ((const float4*)(x + (size_t)row * 1024))[t];
  float s = v.x + v.y + v.z + v.w;
  float s2 = v.x * v.x + v.y * v.y + v.z * v.z + v.w * v.w;
  for (int o = 32; o > 0; o >>= 1) {
    s += __shfl_xor(s, o, 64);
    s2 += __shfl_xor(s2, o, 64);
  }
  __shared__ float red[8];
  const int w = t >> 6;
  if ((t & 63) == 0) { red[w] = s; red[4 + w] = s2; }
  __syncthreads();
  s = red[0] + red[1] + red[2] + red[3];
  s2 = red[4] + red[5] + red[6] + red[7];
  const float mu = s * (1.f / 1024.f);
  const float var = s2 * (1.f / 1024.f) - mu * mu;
  const float rs = rsqrtf(var + 1e-5f);
  const float4 gg = ((const float4*)g)[t];
  const float4 bb = ((const float4*)b)[t];
  ushort4 o4;
  o4.x = f2bf((v.x - mu) * rs * gg.x + bb.x);
  o4.y = f2bf((v.y - mu) * rs * gg.y + bb.y);
  o4.z = f2bf((v.z - mu) * rs * gg.z + bb.z);
  o4.w = f2bf((v.w - mu) * rs * gg.w + bb.w);
  ((ushort4*)(out + (size_t)row * 1024))[t] = o4;
}

// ----------------------------------- GEMM ----------------------------------
// C = A[M][K](bf16) * Bt[N][K](bf16)^T, BK=64 (two packed 32-k half-tiles).
// 256 thr, 4 waves 2x2; wave tile (BM/2)x(BN/2); 16x16x32 MFMA.
// 1D grid with XCD swizzle: xcd=bid&7 owns M-stripe [xcd*MT/8, ...), n-fast.
enum { MODE_QKV = 0, MODE_RES = 1, MODE_GELU = 2 };

// (1/sqrt(64)) * log2(e) folded into Q at QKV epilogue (exp2-domain softmax).
#define QSCALE 0.18033688011112043f

template <int BM, int BN, int MODE>
__global__ __launch_bounds__(256) void gemm_kernel(
    const unsigned short* __restrict__ A, const unsigned short* __restrict__ Bt,
    const float* __restrict__ bias0, const float* __restrict__ bias1,
    const float* __restrict__ bias2, const float* __restrict__ residual,
    void* __restrict__ out0, void* __restrict__ out1, void* __restrict__ out2,
    int M, int N, int K) {
  constexpr int MI = BM / 32;  // m-subtiles per wave
  constexpr int NI = BN / 32;  // n-subtiles per wave
  __shared__ __align__(16) unsigned short As[2][BM * 32];
  __shared__ __align__(16) unsigned short Bs[2][BN * 32];
  const int t = threadIdx.x;

  // XCD-aware tile swizzle (heuristic: consecutive bids round-robin XCDs).
  const int NT = N / BN, MT = M / BM;
  const int bid = blockIdx.x;
  const int xcd = bid & 7, local = bid >> 3;
  const int mt = xcd * (MT >> 3) + local / NT;
  const int nt_ = local % NT;
  const int m0 = mt * BM, n0 = nt_ * BN;

  const int l = t & 63, w = t >> 6;
  const int wm = (w >> 1) * (BM / 2), wn = (w & 1) * (BN / 2);
  const int lr = l & 15, lq = l >> 4;

  f32x4 acc[MI][NI];
#pragma unroll
  for (int i = 0; i < MI; i++)
#pragma unroll
    for (int j = 0; j < NI; j++) {
      f32x4 z = {0.f, 0.f, 0.f, 0.f};
      acc[i][j] = z;
    }

  for (int k0 = 0; k0 < K; k0 += 64) {
    __syncthreads();
#pragma unroll
    for (int h = 0; h < 2; h++)
#pragma unroll
      for (int s = 0; s < BM / 64; s++) {
        const int c = t + s * 256;
        const int row = c >> 2, k8 = (c & 3) * 8;
        async_copy16(&A[(size_t)(m0 + row) * K + k0 + h * 32 + k8],
                     &As[h][c * 8]);
      }
#pragma unroll
    for (int h = 0; h < 2; h++)
#pragma unroll
      for (int s = 0; s < BN / 64; s++) {
        const int c = t + s * 256;
        const int row = c >> 2, k8 = (c & 3) * 8;
        async_copy16(&Bt[(size_t)(n0 + row) * K + k0 + h * 32 + k8],
                     &Bs[h][c * 8]);
      }
    __syncthreads();
#pragma unroll
    for (int kk = 0; kk < 2; kk++) {
      bf16x8 af[MI], bf[NI];
#pragma unroll
      for (int mi = 0; mi < MI; mi++)
        af[mi] = ld_bf16x8(&As[kk][(wm + mi * 16 + lr) * 32 + lq * 8]);
#pragma unroll
      for (int ni = 0; ni < NI; ni++)
        bf[ni] = ld_bf16x8(&Bs[kk][(wn + ni * 16 + lr) * 32 + lq * 8]);
#pragma unroll
      for (int mi = 0; mi < MI; mi++)
#pragma unroll
        for (int ni = 0; ni < NI; ni++)
          acc[mi][ni] = __builtin_amdgcn_mfma_f32_16x16x32_bf16(
              af[mi], bf[ni], acc[mi][ni], 0, 0, 0);
    }
  }

#pragma unroll
  for (int mi = 0; mi < MI; mi++) {
#pragma unroll
    for (int ni = 0; ni < NI; ni++) {
#pragma unroll
      for (int i = 0; i < 4; i++) {
        const int gm = m0 + wm + mi * 16 + lq * 4 + i;
        const int gn = n0 + wn + ni * 16 + lr;
        const float v = acc[mi][ni][i];
        if (MODE == MODE_QKV) {
          const int sel = gn >> 10, cn = gn & 1023;
          const float* bb = sel == 0 ? bias0 : (sel == 1 ? bias1 : bias2);
          unsigned short* dst =
              (unsigned short*)(sel == 0 ? out0 : (sel == 1 ? out1 : out2));
          float u = v + bb[cn];
          if (sel == 0) u *= QSCALE;  // fold softmax scale into Q
          dst[(size_t)gm * 1024 + cn] = f2bf(u);
        } else if (MODE == MODE_RES) {
          ((float*)out0)[(size_t)gm * N + gn] =
              v + bias0[gn] + residual[(size_t)gm * N + gn];
        } else {  // MODE_GELU, exact
          const float u = v + bias0[gn];
          const float ge = 0.5f * u * (1.f + erff(u * 0.70710678118654752f));
          ((unsigned short*)out0)[(size_t)gm * N + gn] = f2bf(ge);
        }
      }
    }
  }
}

// ------------------------------ flash attention ----------------------------
// grid (32 q-tiles of 64, 32 b*h). Q pre-scaled by QSCALE. S^T scheme.
// Block: 64 queries, 4 waves x 16 q. Key tiles of 64. LDS 27KB -> 4-5
// blocks/CU co-resident (TLP fills barrier drains).
__global__ __launch_bounds__(256) void attn_kernel(
    const unsigned short* __restrict__ Q, const unsigned short* __restrict__ Kt,
    const unsigned short* __restrict__ Vt, unsigned short* __restrict__ O) {
  __shared__ __align__(16) unsigned short QPs[64 * 72];  // Qs then Ps
  __shared__ __align__(16) unsigned short Ks[64 * 72];
  __shared__ __align__(16) unsigned short Vs[64 * 72];
  const int qt = blockIdx.x;
  const int bh = blockIdx.y;
  const int bb = bh >> 4, h = bh & 15;
  const int t = threadIdx.x, l = t & 63, w = t >> 6;
  const int lr = l & 15, lq = l >> 4;
  const size_t rowBase = (size_t)bb * 2048;
  const int col0 = h * 64;

  // stage Q tile (64 x 64)
#pragma unroll
  for (int s = 0; s < 2; s++) {
    const int c = t + s * 256;
    const int r = c >> 3, c8 = (c & 7) * 8;
    *(uint4*)&QPs[r * 72 + c8] =
        *(const uint4*)&Q[(rowBase + qt * 64 + r) * 1024 + col0 + c8];
  }
  __syncthreads();
  bf16x8 qf[2];
#pragma unroll
  for (int kk = 0; kk < 2; kk++)
    qf[kk] = ld_bf16x8(&QPs[(w * 16 + lr) * 72 + kk * 32 + lq * 8]);
  // QPs now dead as Q; reused as Ps (loop-top barrier guards).

  f32x4 oacc[4];
#pragma unroll
  for (int nt = 0; nt < 4; nt++) {
    f32x4 z = {0.f, 0.f, 0.f, 0.f};
    oacc[nt] = z;
  }
  float mi_ = -1e30f;
  float lp = 0.f;

  for (int kt = 0; kt < 2048; kt += 64) {
    __syncthreads();
#pragma unroll
    for (int s = 0; s < 2; s++) {
      const int c = t + s * 256;
      const int r = c >> 3, c8 = (c & 7) * 8;
      *(uint4*)&Ks[r * 72 + c8] =
          *(const uint4*)&Kt[(rowBase + kt + r) * 1024 + col0 + c8];
      *(uint4*)&Vs[r * 72 + c8] =
          *(const uint4*)&Vt[((size_t)bh * 64 + r) * 2048 + kt + c8];
    }
    __syncthreads();

    // S^T[key][q] = mfma(kf, qf): col=q(lr), rows=keys.
    f32x4 st[4];
#pragma unroll
    for (int nt = 0; nt < 4; nt++) {
      f32x4 z = {0.f, 0.f, 0.f, 0.f};
      st[nt] = z;
    }
#pragma unroll
    for (int nt = 0; nt < 4; nt++)
#pragma unroll
      for (int kk = 0; kk < 2; kk++) {
        bf16x8 kf = ld_bf16x8(&Ks[(nt * 16 + lr) * 72 + kk * 32 + lq * 8]);
        st[nt] = __builtin_amdgcn_mfma_f32_16x16x32_bf16(kf, qf[kk], st[nt], 0, 0, 0);
      }

    // online softmax (exp2 domain); lane's query q = lr, 16 keys in regs.
    float mx = st[0][0];
#pragma unroll
    for (int nt = 0; nt < 4; nt++)
#pragma unroll
      for (int i = 0; i < 4; i++) mx = fmaxf(mx, st[nt][i]);
    mx = fmaxf(mx, __shfl_xor(mx, 16, 64));
    mx = fmaxf(mx, __shfl_xor(mx, 32, 64));
    const float mnew = fmaxf(mi_, mx);
    const float alpha = exp2f(mi_ - mnew);
    mi_ = mnew;
    float rsum = 0.f;
#pragma unroll
    for (int nt = 0; nt < 4; nt++)
#pragma unroll
      for (int i = 0; i < 4; i++) {
        const float p = exp2f(st[nt][i] - mnew);
        st[nt][i] = p;
        rsum += p;
      }
    lp = lp * alpha + rsum;
#pragma unroll
    for (int nt = 0; nt < 4; nt++) oacc[nt] *= alpha;

    // P[q][key] -> Ps (b64 writes, bf16 truncation pack). Wave-private rows.
#pragma unroll
    for (int nt = 0; nt < 4; nt++) {
      uint2 pk;
      pk.x = __builtin_amdgcn_perm(fbits(st[nt][1]), fbits(st[nt][0]), 0x07060302u);
      pk.y = __builtin_amdgcn_perm(fbits(st[nt][3]), fbits(st[nt][2]), 0x07060302u);
      *(uint2*)&QPs[(w * 16 + lr) * 72 + nt * 16 + lq * 4] = pk;
    }

    // O += P (A-op) * V (B-op from V^T rows).
#pragma unroll
    for (int kb = 0; kb < 2; kb++) {
      bf16x8 pf = ld_bf16x8(&QPs[(w * 16 + lr) * 72 + kb * 32 + lq * 8]);
#pragma unroll
      for (int nt = 0; nt < 4; nt++) {
        bf16x8 vf = ld_bf16x8(&Vs[(nt * 16 + lr) * 72 + kb * 32 + lq * 8]);
        oacc[nt] = __builtin_amdgcn_mfma_f32_16x16x32_bf16(pf, vf, oacc[nt], 0, 0, 0);
      }
    }
  }

  float li = lp;
  li += __shfl_xor(li, 16, 64);
  li += __shfl_xor(li, 32, 64);
  const float inv = 1.f / li;
#pragma unroll
  for (int nt = 0; nt < 4; nt++)
#pragma unroll
    for (int i = 0; i < 4; i++) {
      const size_t orow = rowBase + qt * 64 + w * 16 + lq * 4 + i;
      const int ocol = col0 + nt * 16 + lr;
      O[orow * 1024 + ocol] = f2bf(oacc[nt][i] * inv);
    }
}

// --------------------------------- launcher --------------------------------
extern "C" void kernel_launch(void* const* d_in, const int* in_sizes, int n_in,
                              void* d_out, int out_size, void* d_ws, size_t ws_size,
                              hipStream_t stream) {
  const float* x    = (const float*)d_in[0];
  const float* Wq   = (const float*)d_in[1];
  const float* bq   = (const float*)d_in[2];
  const float* Wk   = (const float*)d_in[3];
  const float* bk   = (const float*)d_in[4];
  const float* Wv   = (const float*)d_in[5];
  const float* bv   = (const float*)d_in[6];
  const float* Wo   = (const float*)d_in[7];
  const float* bo   = (const float*)d_in[8];
  const float* W1   = (const float*)d_in[9];
  const float* b1   = (const float*)d_in[10];
  const float* W2   = (const float*)d_in[11];
  const float* b2   = (const float*)d_in[12];
  const float* ln1g = (const float*)d_in[13];
  const float* ln1b = (const float*)d_in[14];
  const float* ln2g = (const float*)d_in[15];
  const float* ln2b = (const float*)d_in[16];

  char* ws = (char*)d_ws;
  const size_t MB = 1024ull * 1024ull;
  unsigned short* WqT = (unsigned short*)(ws + 0 * MB);   // 2MB  \  contiguous:
  unsigned short* WkT = (unsigned short*)(ws + 2 * MB);   // 2MB   } fused QKV B
  unsigned short* WvT = (unsigned short*)(ws + 4 * MB);   // 2MB  /  [3072][1024]
  unsigned short* WoT = (unsigned short*)(ws + 6 * MB);   // 2MB
  unsigned short* W1T = (unsigned short*)(ws + 8 * MB);   // 8MB [4096][1024]
  unsigned short* W2T = (unsigned short*)(ws + 16 * MB);  // 8MB [1024][4096]
  unsigned short* xn  = (unsigned short*)(ws + 24 * MB);  // 8MB
  unsigned short* Qb  = (unsigned short*)(ws + 32 * MB);  // 8MB (pre-scaled)
  unsigned short* Kb  = (unsigned short*)(ws + 40 * MB);  // 8MB
  unsigned short* Vb  = (unsigned short*)(ws + 48 * MB);  // 8MB
  unsigned short* Ob  = (unsigned short*)(ws + 56 * MB);  // 8MB
  float*          x1  = (float*)(ws + 64 * MB);           // 16MB
  unsigned short* h2  = (unsigned short*)(ws + 80 * MB);  // 8MB  (total 88MB)
  // aliases (dead regions reused):
  unsigned short* VtG = (unsigned short*)(ws + 24 * MB);  // 8MB alias xn
  unsigned short* Hb  = (unsigned short*)(ws + 24 * MB);  // 32MB alias xn/Q/K/V

  const dim3 blk(256);

  transpose_cast_kernel<<<dim3(32, 32), blk, 0, stream>>>(Wq, WqT, 1024, 1024);
  transpose_cast_kernel<<<dim3(32, 32), blk, 0, stream>>>(Wk, WkT, 1024, 1024);
  transpose_cast_kernel<<<dim3(32, 32), blk, 0, stream>>>(Wv, WvT, 1024, 1024);
  transpose_cast_kernel<<<dim3(32, 32), blk, 0, stream>>>(Wo, WoT, 1024, 1024);
  transpose_cast_kernel<<<dim3(128, 32), blk, 0, stream>>>(W1, W1T, 4096, 1024);
  transpose_cast_kernel<<<dim3(32, 128), blk, 0, stream>>>(W2, W2T, 1024, 4096);

  ln_kernel<<<4096, blk, 0, stream>>>(x, ln1g, ln1b, xn);

  gemm_kernel<128, 128, MODE_QKV><<<dim3(24 * 32), blk, 0, stream>>>(
      xn, WqT, bq, bk, bv, nullptr, Qb, Kb, Vb, 4096, 3072, 1024);

  transpose_v_kernel<<<dim3(64, 2, 32), blk, 0, stream>>>(Vb, VtG);

  attn_kernel<<<dim3(32, 32), blk, 0, stream>>>(Qb, Kb, VtG, Ob);

  gemm_kernel<64, 128, MODE_RES><<<dim3(8 * 64), blk, 0, stream>>>(
      Ob, WoT, bo, nullptr, nullptr, x, x1, nullptr, nullptr, 4096, 1024, 1024);

  ln_kernel<<<4096, blk, 0, stream>>>(x1, ln2g, ln2b, h2);

  gemm_kernel<128, 128, MODE_GELU><<<dim3(32 * 32), blk, 0, stream>>>(
      h2, W1T, b1, nullptr, nullptr, nullptr, Hb, nullptr, nullptr, 4096, 4096, 1024);

  gemm_kernel<64, 128, MODE_RES><<<dim3(8 * 64), blk, 0, stream>>>(
      Hb, W2T, b2, nullptr, nullptr, x1, (float*)d_out, nullptr, nullptr, 4096, 1024, 4096);
}

// Round 6
// 424.392 us; speedup vs baseline: 1.2783x; 1.0007x over previous
//
#include <hip/hip_runtime.h>
#include <hip/hip_bf16.h>
#include <math.h>

// ---------------------------------------------------------------------------
// Transformer block (B=2, T=2048, C=1024, NH=16, hd=64), fp32 in/out.
// R6 changes vs R5:
//  - GEMM: explicit LDS double-buffer. Loads for tile k+1 issued right after
//    the loop-top barrier; compute on tile k covers their latency (the
//    structural vmcnt(0) drain previously exposed full HBM/L2 latency every
//    iter -> MfmaUtil 14%). 64KB LDS on 128x128 (2 blocks/CU) -- accepted:
//    R5 proved TLP isn't the limiter, intra-block latency hiding is.
//  - Attention: back to 128-q tile (R4 > R5) and KT=128 key tiles: halves
//    barriers/staging rounds/softmax fixed costs per score. P-pack + PV in
//    two 64-key halves (wave-private Ps, stride 72). LDS 53KB, 3 blocks/CU.
// ---------------------------------------------------------------------------

typedef __bf16 bf16x8 __attribute__((ext_vector_type(8)));
typedef float f32x4 __attribute__((ext_vector_type(4)));

__device__ __forceinline__ unsigned short f2bf(float f) {
  union { float f; unsigned int u; } v; v.f = f;
  unsigned int u = v.u;
  unsigned int r = (u + 0x7fffu + ((u >> 16) & 1u)) >> 16;  // RNE
  return (unsigned short)r;
}

__device__ __forceinline__ unsigned int fbits(float f) {
  union { float f; unsigned int u; } v; v.f = f;
  return v.u;
}

__device__ __forceinline__ bf16x8 ld_bf16x8(const unsigned short* p) {
  union { uint4 u; bf16x8 v; } x;
  x.u = *(const uint4*)p;
  return x.v;
}

// async 16B global->LDS (DMA). LDS dest is wave-uniform base + lane*16.
__device__ __forceinline__ void async_copy16(const void* g, void* l) {
  __builtin_amdgcn_global_load_lds(
      (const __attribute__((address_space(1))) void*)g,
      (__attribute__((address_space(3))) void*)l, 16, 0, 0);
}

// --------------------------- weight transpose+cast -------------------------
__global__ __launch_bounds__(256) void transpose_cast_kernel(
    const float* __restrict__ W, unsigned short* __restrict__ Wt, int N, int K) {
  __shared__ unsigned short tile[32][33];
  const int n0 = blockIdx.x * 32, k0 = blockIdx.y * 32;
  const int t = threadIdx.x;
  const int r = t >> 3, cq = (t & 7) * 4;
  float4 v = *(const float4*)&W[(size_t)(k0 + r) * N + n0 + cq];
  tile[cq + 0][r] = f2bf(v.x);
  tile[cq + 1][r] = f2bf(v.y);
  tile[cq + 2][r] = f2bf(v.z);
  tile[cq + 3][r] = f2bf(v.w);
  __syncthreads();
  ushort4 o;
  o.x = tile[r][cq + 0];
  o.y = tile[r][cq + 1];
  o.z = tile[r][cq + 2];
  o.w = tile[r][cq + 3];
  *(ushort4*)&Wt[(size_t)(n0 + r) * K + k0 + cq] = o;
}

// ------------------------------- V transpose -------------------------------
// V bf16 [4096][1024] -> Vt bf16 [32 bh][64 d][2048 k]. grid (64, 2, 32).
__global__ __launch_bounds__(256) void transpose_v_kernel(
    const unsigned short* __restrict__ V, unsigned short* __restrict__ Vt) {
  __shared__ unsigned short tile[32][36];
  const int kt = blockIdx.x * 32;
  const int d0 = blockIdx.y * 32;
  const int bh = blockIdx.z;
  const int bb = bh >> 4, h = bh & 15;
  const int t = threadIdx.x;
  const int r = t >> 3, c4 = (t & 7) * 4;
  ushort4 v = *(const ushort4*)&V[((size_t)bb * 2048 + kt + r) * 1024 + h * 64 + d0 + c4];
  tile[c4 + 0][r] = v.x;
  tile[c4 + 1][r] = v.y;
  tile[c4 + 2][r] = v.z;
  tile[c4 + 3][r] = v.w;
  __syncthreads();
  ushort4 o;
  o.x = tile[r][c4 + 0];
  o.y = tile[r][c4 + 1];
  o.z = tile[r][c4 + 2];
  o.w = tile[r][c4 + 3];
  *(ushort4*)&Vt[((size_t)bh * 64 + d0 + r) * 2048 + kt + c4] = o;
}

// --------------------------------- layernorm -------------------------------
__global__ __launch_bounds__(256) void ln_kernel(
    const float* __restrict__ x, const float* __restrict__ g,
    const float* __restrict__ b, unsigned short* __restrict__ out) {
  const int row = blockIdx.x, t = threadIdx.x;
  const float4 v = ((const float4*)(x + (size_t)row * 1024))[t];
  float s = v.x + v.y + v.z + v.w;
  float s2 = v.x * v.x + v.y * v.y + v.z * v.z + v.w * v.w;
  for (int o = 32; o > 0; o >>= 1) {
    s += __shfl_xor(s, o, 64);
    s2 += __shfl_xor(s2, o, 64);
  }
  __shared__ float red[8];
  const int w = t >> 6;
  if ((t & 63) == 0) { red[w] = s; red[4 + w] = s2; }
  __syncthreads();
  s = red[0] + red[1] + red[2] + red[3];
  s2 = red[4] + red[5] + red[6] + red[7];
  const float mu = s * (1.f / 1024.f);
  const float var = s2 * (1.f / 1024.f) - mu * mu;
  const float rs = rsqrtf(var + 1e-5f);
  const float4 gg = ((const float4*)g)[t];
  const float4 bb = ((const float4*)b)[t];
  ushort4 o4;
  o4.x = f2bf((v.x - mu) * rs * gg.x + bb.x);
  o4.y = f2bf((v.y - mu) * rs * gg.y + bb.y);
  o4.z = f2bf((v.z - mu) * rs * gg.z + bb.z);
  o4.w = f2bf((v.w - mu) * rs * gg.w + bb.w);
  ((ushort4*)(out + (size_t)row * 1024))[t] = o4;
}

// ----------------------------------- GEMM ----------------------------------
// C = A[M][K](bf16) * Bt[N][K](bf16)^T, BK=64, double-buffered LDS.
// 256 thr, 4 waves 2x2; wave tile (BM/2)x(BN/2); 16x16x32 MFMA.
// 1D grid with XCD swizzle (neutral so far, kept).
enum { MODE_QKV = 0, MODE_RES = 1, MODE_GELU = 2 };

// (1/sqrt(64)) * log2(e) folded into Q at QKV epilogue (exp2-domain softmax).
#define QSCALE 0.18033688011112043f

template <int BM, int BN, int MODE>
__global__ __launch_bounds__(256) void gemm_kernel(
    const unsigned short* __restrict__ A, const unsigned short* __restrict__ Bt,
    const float* __restrict__ bias0, const float* __restrict__ bias1,
    const float* __restrict__ bias2, const float* __restrict__ residual,
    void* __restrict__ out0, void* __restrict__ out1, void* __restrict__ out2,
    int M, int N, int K) {
  constexpr int MI = BM / 32;  // m-subtiles per wave
  constexpr int NI = BN / 32;  // n-subtiles per wave
  // [buffer][k-half][tile]: per-half layout keeps global_load_lds lane
  // contiguity AND stride-32 frag reads.
  __shared__ __align__(16) unsigned short As[2][2][BM * 32];
  __shared__ __align__(16) unsigned short Bs[2][2][BN * 32];
  const int t = threadIdx.x;

  const int NT = N / BN, MT = M / BM;
  const int bid = blockIdx.x;
  const int xcd = bid & 7, local = bid >> 3;
  const int mt = xcd * (MT >> 3) + local / NT;
  const int nt_ = local % NT;
  const int m0 = mt * BM, n0 = nt_ * BN;

  const int l = t & 63, w = t >> 6;
  const int wm = (w >> 1) * (BM / 2), wn = (w & 1) * (BN / 2);
  const int lr = l & 15, lq = l >> 4;

  f32x4 acc[MI][NI];
#pragma unroll
  for (int i = 0; i < MI; i++)
#pragma unroll
    for (int j = 0; j < NI; j++) {
      f32x4 z = {0.f, 0.f, 0.f, 0.f};
      acc[i][j] = z;
    }

  // issue loads for k-tile into buffer p
  auto issue = [&](int k0, int p) {
#pragma unroll
    for (int h = 0; h < 2; h++)
#pragma unroll
      for (int s = 0; s < BM / 64; s++) {
        const int c = t + s * 256;
        const int row = c >> 2, k8 = (c & 3) * 8;
        async_copy16(&A[(size_t)(m0 + row) * K + k0 + h * 32 + k8],
                     &As[p][h][c * 8]);
      }
#pragma unroll
    for (int h = 0; h < 2; h++)
#pragma unroll
      for (int s = 0; s < BN / 64; s++) {
        const int c = t + s * 256;
        const int row = c >> 2, k8 = (c & 3) * 8;
        async_copy16(&Bt[(size_t)(n0 + row) * K + k0 + h * 32 + k8],
                     &Bs[p][h][c * 8]);
      }
  };

  issue(0, 0);
  int p = 0;
  for (int k0 = 0; k0 < K; k0 += 64) {
    __syncthreads();  // buffer p ready (own loads drained; peers arrived)
    if (k0 + 64 < K) issue(k0 + 64, p ^ 1);  // prefetch: latency covered below
#pragma unroll
    for (int kk = 0; kk < 2; kk++) {
      bf16x8 af[MI], bf[NI];
#pragma unroll
      for (int mi = 0; mi < MI; mi++)
        af[mi] = ld_bf16x8(&As[p][kk][(wm + mi * 16 + lr) * 32 + lq * 8]);
#pragma unroll
      for (int ni = 0; ni < NI; ni++)
        bf[ni] = ld_bf16x8(&Bs[p][kk][(wn + ni * 16 + lr) * 32 + lq * 8]);
#pragma unroll
      for (int mi = 0; mi < MI; mi++)
#pragma unroll
        for (int ni = 0; ni < NI; ni++)
          acc[mi][ni] = __builtin_amdgcn_mfma_f32_16x16x32_bf16(
              af[mi], bf[ni], acc[mi][ni], 0, 0, 0);
    }
    p ^= 1;
  }

#pragma unroll
  for (int mi = 0; mi < MI; mi++) {
#pragma unroll
    for (int ni = 0; ni < NI; ni++) {
#pragma unroll
      for (int i = 0; i < 4; i++) {
        const int gm = m0 + wm + mi * 16 + lq * 4 + i;
        const int gn = n0 + wn + ni * 16 + lr;
        const float v = acc[mi][ni][i];
        if (MODE == MODE_QKV) {
          const int sel = gn >> 10, cn = gn & 1023;
          const float* bb = sel == 0 ? bias0 : (sel == 1 ? bias1 : bias2);
          unsigned short* dst =
              (unsigned short*)(sel == 0 ? out0 : (sel == 1 ? out1 : out2));
          float u = v + bb[cn];
          if (sel == 0) u *= QSCALE;  // fold softmax scale into Q
          dst[(size_t)gm * 1024 + cn] = f2bf(u);
        } else if (MODE == MODE_RES) {
          ((float*)out0)[(size_t)gm * N + gn] =
              v + bias0[gn] + residual[(size_t)gm * N + gn];
        } else {  // MODE_GELU, exact
          const float u = v + bias0[gn];
          const float ge = 0.5f * u * (1.f + erff(u * 0.70710678118654752f));
          ((unsigned short*)out0)[(size_t)gm * N + gn] = f2bf(ge);
        }
      }
    }
  }
}

// ------------------------------ flash attention ----------------------------
// grid (16 q-tiles of 128, 32 b*h). Q pre-scaled by QSCALE. S^T scheme.
// Block: 128 queries, 4 waves x 32 q (2 subtiles of 16). KT=128 key tiles
// (halved barriers/staging/softmax fixed costs). P-pack + PV in two 64-key
// halves through wave-private Ps (stride 72). LDS 53KB -> 3 blocks/CU.
__global__ __launch_bounds__(256) void attn_kernel(
    const unsigned short* __restrict__ Q, const unsigned short* __restrict__ Kt,
    const unsigned short* __restrict__ Vt, unsigned short* __restrict__ O) {
  __shared__ __align__(16) unsigned short QPs[128 * 72];  // Qs then Ps
  __shared__ __align__(16) unsigned short Ks[128 * 72];
  __shared__ __align__(16) unsigned short Vs[64 * 136];   // V^T: [d][k]
  const int qt = blockIdx.x;
  const int bh = blockIdx.y;
  const int bb = bh >> 4, h = bh & 15;
  const int t = threadIdx.x, l = t & 63, w = t >> 6;
  const int lr = l & 15, lq = l >> 4;
  const size_t rowBase = (size_t)bb * 2048;
  const int col0 = h * 64;

  // stage Q tile (128 x 64)
#pragma unroll
  for (int s = 0; s < 4; s++) {
    const int c = t + s * 256;
    const int r = c >> 3, c8 = (c & 7) * 8;
    *(uint4*)&QPs[r * 72 + c8] =
        *(const uint4*)&Q[(rowBase + qt * 128 + r) * 1024 + col0 + c8];
  }
  __syncthreads();
  bf16x8 qf[2][2];
#pragma unroll
  for (int s = 0; s < 2; s++)
#pragma unroll
    for (int kk = 0; kk < 2; kk++)
      qf[s][kk] = ld_bf16x8(&QPs[(w * 32 + s * 16 + lr) * 72 + kk * 32 + lq * 8]);
  // QPs now dead as Q; reused as Ps (loop-top barrier guards: every wave's
  // qf reads complete before its barrier arrival).

  f32x4 oacc[2][4];
#pragma unroll
  for (int s = 0; s < 2; s++)
#pragma unroll
    for (int nt = 0; nt < 4; nt++) {
      f32x4 z = {0.f, 0.f, 0.f, 0.f};
      oacc[s][nt] = z;
    }
  float mi_[2] = {-1e30f, -1e30f};
  float lp[2] = {0.f, 0.f};

  for (int kt = 0; kt < 2048; kt += 128) {
    __syncthreads();
    // stage K (128 rows x 64 cols) and V^T (64 rows x 128 cols)
#pragma unroll
    for (int s = 0; s < 4; s++) {
      const int c = t + s * 256;
      const int r = c >> 3, c8 = (c & 7) * 8;
      *(uint4*)&Ks[r * 72 + c8] =
          *(const uint4*)&Kt[(rowBase + kt + r) * 1024 + col0 + c8];
      const int vr = c >> 4, vc = (c & 15) * 8;
      *(uint4*)&Vs[vr * 136 + vc] =
          *(const uint4*)&Vt[((size_t)bh * 64 + vr) * 2048 + kt + vc];
    }
    __syncthreads();

    // S^T[key][q]: 8 key-subtiles x 2 q-subtiles; kf shared across subtiles.
    f32x4 st[2][8];
#pragma unroll
    for (int s = 0; s < 2; s++)
#pragma unroll
      for (int nt = 0; nt < 8; nt++) {
        f32x4 z = {0.f, 0.f, 0.f, 0.f};
        st[s][nt] = z;
      }
#pragma unroll
    for (int nt = 0; nt < 8; nt++)
#pragma unroll
      for (int kk = 0; kk < 2; kk++) {
        bf16x8 kf = ld_bf16x8(&Ks[(nt * 16 + lr) * 72 + kk * 32 + lq * 8]);
        st[0][nt] = __builtin_amdgcn_mfma_f32_16x16x32_bf16(kf, qf[0][kk], st[0][nt], 0, 0, 0);
        st[1][nt] = __builtin_amdgcn_mfma_f32_16x16x32_bf16(kf, qf[1][kk], st[1][nt], 0, 0, 0);
      }

    // online softmax (exp2 domain); lane's query q=lr per subtile; 32 keys.
#pragma unroll
    for (int s = 0; s < 2; s++) {
      float mx = st[s][0][0];
#pragma unroll
      for (int nt = 0; nt < 8; nt++)
#pragma unroll
        for (int i = 0; i < 4; i++) mx = fmaxf(mx, st[s][nt][i]);
      mx = fmaxf(mx, __shfl_xor(mx, 16, 64));
      mx = fmaxf(mx, __shfl_xor(mx, 32, 64));
      const float mnew = fmaxf(mi_[s], mx);
      const float alpha = exp2f(mi_[s] - mnew);
      mi_[s] = mnew;
      float rsum = 0.f;
#pragma unroll
      for (int nt = 0; nt < 8; nt++)
#pragma unroll
        for (int i = 0; i < 4; i++) {
          const float p = exp2f(st[s][nt][i] - mnew);
          st[s][nt][i] = p;
          rsum += p;
        }
      lp[s] = lp[s] * alpha + rsum;
#pragma unroll
      for (int nt = 0; nt < 4; nt++) oacc[s][nt] *= alpha;
    }

    // pack + PV in two 64-key halves (wave-private Ps rows; in-wave LDS
    // ordering makes write->read->overwrite safe without barriers).
#pragma unroll
    for (int hh = 0; hh < 2; hh++) {
#pragma unroll
      for (int s = 0; s < 2; s++)
#pragma unroll
        for (int n4 = 0; n4 < 4; n4++) {
          const int nt = hh * 4 + n4;
          uint2 pk;
          pk.x = __builtin_amdgcn_perm(fbits(st[s][nt][1]), fbits(st[s][nt][0]), 0x07060302u);
          pk.y = __builtin_amdgcn_perm(fbits(st[s][nt][3]), fbits(st[s][nt][2]), 0x07060302u);
          *(uint2*)&QPs[(w * 32 + s * 16 + lr) * 72 + n4 * 16 + lq * 4] = pk;
        }
#pragma unroll
      for (int kb = 0; kb < 2; kb++) {
        bf16x8 pf0 = ld_bf16x8(&QPs[(w * 32 + lr) * 72 + kb * 32 + lq * 8]);
        bf16x8 pf1 = ld_bf16x8(&QPs[(w * 32 + 16 + lr) * 72 + kb * 32 + lq * 8]);
#pragma unroll
        for (int n4 = 0; n4 < 4; n4++) {
          bf16x8 vf = ld_bf16x8(&Vs[(n4 * 16 + lr) * 136 + hh * 64 + kb * 32 + lq * 8]);
          oacc[0][n4] = __builtin_amdgcn_mfma_f32_16x16x32_bf16(pf0, vf, oacc[0][n4], 0, 0, 0);
          oacc[1][n4] = __builtin_amdgcn_mfma_f32_16x16x32_bf16(pf1, vf, oacc[1][n4], 0, 0, 0);
        }
      }
    }
  }

#pragma unroll
  for (int s = 0; s < 2; s++) {
    float li = lp[s];
    li += __shfl_xor(li, 16, 64);
    li += __shfl_xor(li, 32, 64);
    const float inv = 1.f / li;
#pragma unroll
    for (int nt = 0; nt < 4; nt++)
#pragma unroll
      for (int i = 0; i < 4; i++) {
        const size_t orow = rowBase + qt * 128 + w * 32 + s * 16 + lq * 4 + i;
        const int ocol = col0 + nt * 16 + lr;
        O[orow * 1024 + ocol] = f2bf(oacc[s][nt][i] * inv);
      }
  }
}

// --------------------------------- launcher --------------------------------
extern "C" void kernel_launch(void* const* d_in, const int* in_sizes, int n_in,
                              void* d_out, int out_size, void* d_ws, size_t ws_size,
                              hipStream_t stream) {
  const float* x    = (const float*)d_in[0];
  const float* Wq   = (const float*)d_in[1];
  const float* bq   = (const float*)d_in[2];
  const float* Wk   = (const float*)d_in[3];
  const float* bk   = (const float*)d_in[4];
  const float* Wv   = (const float*)d_in[5];
  const float* bv   = (const float*)d_in[6];
  const float* Wo   = (const float*)d_in[7];
  const float* bo   = (const float*)d_in[8];
  const float* W1   = (const float*)d_in[9];
  const float* b1   = (const float*)d_in[10];
  const float* W2   = (const float*)d_in[11];
  const float* b2   = (const float*)d_in[12];
  const float* ln1g = (const float*)d_in[13];
  const float* ln1b = (const float*)d_in[14];
  const float* ln2g = (const float*)d_in[15];
  const float* ln2b = (const float*)d_in[16];

  char* ws = (char*)d_ws;
  const size_t MB = 1024ull * 1024ull;
  unsigned short* WqT = (unsigned short*)(ws + 0 * MB);   // 2MB  \  contiguous:
  unsigned short* WkT = (unsigned short*)(ws + 2 * MB);   // 2MB   } fused QKV B
  unsigned short* WvT = (unsigned short*)(ws + 4 * MB);   // 2MB  /  [3072][1024]
  unsigned short* WoT = (unsigned short*)(ws + 6 * MB);   // 2MB
  unsigned short* W1T = (unsigned short*)(ws + 8 * MB);   // 8MB [4096][1024]
  unsigned short* W2T = (unsigned short*)(ws + 16 * MB);  // 8MB [1024][4096]
  unsigned short* xn  = (unsigned short*)(ws + 24 * MB);  // 8MB
  unsigned short* Qb  = (unsigned short*)(ws + 32 * MB);  // 8MB (pre-scaled)
  unsigned short* Kb  = (unsigned short*)(ws + 40 * MB);  // 8MB
  unsigned short* Vb  = (unsigned short*)(ws + 48 * MB);  // 8MB
  unsigned short* Ob  = (unsigned short*)(ws + 56 * MB);  // 8MB
  float*          x1  = (float*)(ws + 64 * MB);           // 16MB
  unsigned short* h2  = (unsigned short*)(ws + 80 * MB);  // 8MB  (total 88MB)
  // aliases (dead regions reused):
  unsigned short* VtG = (unsigned short*)(ws + 24 * MB);  // 8MB alias xn
  unsigned short* Hb  = (unsigned short*)(ws + 24 * MB);  // 32MB alias xn/Q/K/V

  const dim3 blk(256);

  transpose_cast_kernel<<<dim3(32, 32), blk, 0, stream>>>(Wq, WqT, 1024, 1024);
  transpose_cast_kernel<<<dim3(32, 32), blk, 0, stream>>>(Wk, WkT, 1024, 1024);
  transpose_cast_kernel<<<dim3(32, 32), blk, 0, stream>>>(Wv, WvT, 1024, 1024);
  transpose_cast_kernel<<<dim3(32, 32), blk, 0, stream>>>(Wo, WoT, 1024, 1024);
  transpose_cast_kernel<<<dim3(128, 32), blk, 0, stream>>>(W1, W1T, 4096, 1024);
  transpose_cast_kernel<<<dim3(32, 128), blk, 0, stream>>>(W2, W2T, 1024, 4096);

  ln_kernel<<<4096, blk, 0, stream>>>(x, ln1g, ln1b, xn);

  gemm_kernel<128, 128, MODE_QKV><<<dim3(24 * 32), blk, 0, stream>>>(
      xn, WqT, bq, bk, bv, nullptr, Qb, Kb, Vb, 4096, 3072, 1024);

  transpose_v_kernel<<<dim3(64, 2, 32), blk, 0, stream>>>(Vb, VtG);

  attn_kernel<<<dim3(16, 32), blk, 0, stream>>>(Qb, Kb, VtG, Ob);

  gemm_kernel<64, 128, MODE_RES><<<dim3(8 * 64), blk, 0, stream>>>(
      Ob, WoT, bo, nullptr, nullptr, x, x1, nullptr, nullptr, 4096, 1024, 1024);

  ln_kernel<<<4096, blk, 0, stream>>>(x1, ln2g, ln2b, h2);

  gemm_kernel<128, 128, MODE_GELU><<<dim3(32 * 32), blk, 0, stream>>>(
      h2, W1T, b1, nullptr, nullptr, nullptr, Hb, nullptr, nullptr, 4096, 4096, 1024);

  gemm_kernel<64, 128, MODE_RES><<<dim3(8 * 64), blk, 0, stream>>>(
      Hb, W2T, b2, nullptr, nullptr, x1, (float*)d_out, nullptr, nullptr, 4096, 1024, 4096);
}